// Round 12
// baseline (354.246 us; speedup 1.0000x reference)
//
#include <hip/hip_runtime.h>
#include <hip/hip_bf16.h>
#include <stdint.h>

// LinearAttention: B=4 T=4096 D=1024 H=16 HD=64
#define T_ 4096
#define M_ 16384   // B*T

typedef __attribute__((ext_vector_type(8))) short short8;   // 8 x bf16
typedef __attribute__((ext_vector_type(4))) float f32x4;

__device__ __forceinline__ short f2b(float f) {
    __hip_bfloat16 h = __float2bfloat16(f);
    return __builtin_bit_cast(short, h);
}
__device__ __forceinline__ float b2f(short s) {
    unsigned int u = ((unsigned int)(unsigned short)s) << 16;
    return __builtin_bit_cast(float, u);
}
// async global->LDS, 16B per lane; LDS dst wave-uniform (HW adds lane*16)
__device__ __forceinline__ void gload16(const void* g, void* l) {
    __builtin_amdgcn_global_load_lds(
        (const __attribute__((address_space(1))) void*)(unsigned long long)(uintptr_t)g,
        (__attribute__((address_space(3))) void*)(unsigned int)(uintptr_t)l,
        16, 0, 0);
}

// ---------------- fp32 -> bf16 converts ----------------
__global__ __launch_bounds__(256) void cvt_x(const float* __restrict__ in,
                                             short* __restrict__ out) {
    long i = ((long)blockIdx.x * 256 + threadIdx.x) * 4;
    float4 f = *(const float4*)(in + i);
    short4 o; o.x = f2b(f.x); o.y = f2b(f.y); o.z = f2b(f.z); o.w = f2b(f.w);
    *(short4*)(out + i) = o;
}

__global__ __launch_bounds__(256) void cvt_weights(
    const float* __restrict__ Wq, const float* __restrict__ Wk,
    const float* __restrict__ Wv, const float* __restrict__ Wo,
    short* __restrict__ wqkvb, short* __restrict__ wob) {
    long i = ((long)blockIdx.x * 256 + threadIdx.x) * 4;
    int region = (int)(i >> 20);
    long off = i & 1048575;
    const float* src = region == 0 ? Wq : region == 1 ? Wk : region == 2 ? Wv : Wo;
    short* dst = region < 3 ? wqkvb + (long)region * 1048576 : wob;
    float4 f = *(const float4*)(src + off);
    short4 o; o.x = f2b(f.x); o.y = f2b(f.y); o.z = f2b(f.z); o.w = f2b(f.w);
    *(short4*)(dst + off) = o;
}

// ---- 256x256 SINGLE-BARRIER-PER-TILE GEMM: C = A[M,K] * Bw[N,K]^T, K=1024 ---
// 8 waves (2M x 4N), per-wave 128x64 out. BK=64, 16 K-tiles. LDS 128KB dbuf.
// R6's proven one-barrier loop (which saturated the LDS pipe at 128² via wave
// desync) at 256² geometry where MFMA (2484 cyc) ~ LDS (2800 cyc) balance.
// Per tile: stage(t+1)->dn | rdAB(d) 24 reads | LGKM0+SCHED0 | 64 MFMA |
//           VMW0 | BAR | SCHED0.
// No mid-tile barriers -> waves slip against each other; one wave's MFMA
// overlaps another's LDS drain on the same SIMD (m114 mechanism).
// Hazards (R6-proven invariants):
//   RAW: own VMW0 -> BAR -> SCHED0 precedes any read of newly staged data.
//   WAR: buf dn's readers (tile t-1) drained at their LGKM0 before their BAR;
//        stage(t+1) into dn issues after that BAR. Cross-wave safe.
//   Reg: mm(t-1) precedes rdAB(t) in program order (R4/R5 lesson).
// XOR swizzle (R6/R8-proven, 0 conflicts) unchanged.
template <int MODE>
__global__ __launch_bounds__(512) void gemm1t(
    const short* __restrict__ A, const short* __restrict__ Bw,
    const int* __restrict__ mask,
    short* __restrict__ oQ, short* __restrict__ oK, short* __restrict__ oV,
    float* __restrict__ oF) {
    extern __shared__ short lds[];   // 65536 shorts = 128KB
    const int tid = threadIdx.x;
    const int wave = tid >> 6, lane = tid & 63;
    const int wm = wave >> 2, wn = wave & 3;

    // bijective XCD swizzle (gridDim.x % 8 == 0 for both modes)
    const int nwg = gridDim.x;
    const int cpx = nwg >> 3;
    const int wg = (blockIdx.x & 7) * cpx + (blockIdx.x >> 3);
    const int bm = wg & 63, bn = wg >> 6;
    const long m0 = (long)bm * 256, n0 = (long)bn * 256;

    f32x4 acc[8][4];
#pragma unroll
    for (int i = 0; i < 8; ++i)
#pragma unroll
        for (int j = 0; j < 4; ++j) acc[i][j] = (f32x4)(0.0f);

    // staging bases: lane l covers row +(l>>3), global col-slot ((l&7)^(l>>3))
    const short* aStageBase = A + (m0 + (lane >> 3)) * 1024 +
                              (((lane & 7) ^ (lane >> 3)) * 8);
    const short* bStageBase = Bw + (n0 + (lane >> 3)) * 1024 +
                              (((lane & 7) ^ (lane >> 3)) * 8);

    // stage tile t (A[256][64] + B[256][64]): 8 gloads/wave
    auto stage = [&](int t) {
        const int d = t & 1;
#pragma unroll
        for (int j = 0; j < 4; ++j) {
            const int r = wave * 8 + j * 64;
            gload16(aStageBase + (long)r * 1024 + t * 64, lds + d * 16384 + r * 64);
            gload16(bStageBase + (long)r * 1024 + t * 64,
                    lds + 32768 + d * 16384 + r * 64);
        }
    };

    // ---- hoisted DS read bases (element offsets into lds) ----
    const int laneR = lane & 15;
    const int sB0 = (((lane >> 4) ^ (lane & 7)) * 8);
    const int cA0 = wm * 8192 + laneR * 64 + sB0;              // kk=0
    const int cA1 = wm * 8192 + laneR * 64 + (sB0 ^ 32);       // kk=1
    const int cB0 = 32768 + (wn >> 1) * 8192 + (wn & 1) * 4096 +
                    laneR * 64 + sB0;
    const int cB1 = 32768 + (wn >> 1) * 8192 + (wn & 1) * 4096 +
                    laneR * 64 + (sB0 ^ 32);

    short8 af[8][2], bf[4][2];
    auto rdAB = [&](int pa0, int pa1, int pb0, int pb1) {
#pragma unroll
        for (int m = 0; m < 8; ++m) {
            af[m][0] = *(const short8*)(lds + pa0 + m * 1024);
            af[m][1] = *(const short8*)(lds + pa1 + m * 1024);
        }
#pragma unroll
        for (int n = 0; n < 4; ++n) {
            bf[n][0] = *(const short8*)(lds + pb0 + n * 1024);
            bf[n][1] = *(const short8*)(lds + pb1 + n * 1024);
        }
    };

#define BAR()    __builtin_amdgcn_s_barrier()
#define LGKM0()  asm volatile("s_waitcnt lgkmcnt(0)" ::: "memory")
#define VMW0()   asm volatile("s_waitcnt vmcnt(0)" ::: "memory")
#define SCHED0() __builtin_amdgcn_sched_barrier(0)

    // -------- prologue: tile0 staged + visible --------
    stage(0);
    VMW0();
    BAR();
    SCHED0();

#pragma unroll 2
    for (int t = 0; t < 16; ++t) {
        const int dofs = (t & 1) * 16384;
        if (t + 1 < 16) stage(t + 1);       // 8 gloads into buf dn (HBM latency
                                            //  hides under reads+MFMA below)
        rdAB(cA0 + dofs, cA1 + dofs, cB0 + dofs, cB1 + dofs);  // 24 ds_reads
        LGKM0();                            // own reads drained
        SCHED0();                           // rule 18: MFMA stays below
        __builtin_amdgcn_s_setprio(1);
#pragma unroll
        for (int kk = 0; kk < 2; ++kk)      // kk-outer: same-acc reuse 32 apart
#pragma unroll
            for (int m = 0; m < 8; ++m)
#pragma unroll
                for (int n = 0; n < 4; ++n)
                    acc[m][n] = __builtin_amdgcn_mfma_f32_16x16x32_bf16(
                        af[m][kk], bf[n][kk], acc[m][n], 0, 0, 0);
        __builtin_amdgcn_s_setprio(0);
        if (t + 1 < 16) VMW0();             // own stage landed
        BAR();                              // staged data cross-wave visible;
        SCHED0();                           //  next iter's reads stay below
    }

    // ---------------- epilogue ----------------
    if (MODE == 0) {
        const int sec = (int)(n0 >> 10);        // 0=Q 1=K 2=V (uniform per block)
        short* outp = sec == 0 ? oQ : (sec == 1 ? oK : oV);
        const long cbase = n0 & 1023;
#pragma unroll
        for (int mi = 0; mi < 8; ++mi) {
#pragma unroll
            for (int r = 0; r < 4; ++r) {
                long gm = m0 + wm * 128 + mi * 16 + (lane >> 4) * 4 + r;
                int mz = (sec >= 1) ? mask[gm] : 0;
#pragma unroll
                for (int ni = 0; ni < 4; ++ni) {
                    long gn = cbase + wn * 64 + ni * 16 + (lane & 15);
                    float v = acc[mi][ni][r];
                    if (sec <= 1) v = (v > 0.f) ? v + 1.f : __expf(v);  // elu+1
                    if (mz) v = 0.f;
                    outp[gm * 1024 + gn] = f2b(v);
                }
            }
        }
    } else {
#pragma unroll
        for (int mi = 0; mi < 8; ++mi)
#pragma unroll
            for (int r = 0; r < 4; ++r) {
                long gm = m0 + wm * 128 + mi * 16 + (lane >> 4) * 4 + r;
#pragma unroll
                for (int ni = 0; ni < 4; ++ni) {
                    long gn = n0 + wn * 64 + ni * 16 + (lane & 15);
                    oF[gm * 1024 + gn] = acc[mi][ni][r];
                }
            }
    }
#undef BAR
#undef LGKM0
#undef VMW0
#undef SCHED0
}

// ---------------- kv partial: kv[bh][dk][dv] += K[t][dk]*V[t][dv] ----------------
__global__ __launch_bounds__(256) void kv_partial(
    const short* __restrict__ Kb, const short* __restrict__ Vb,
    float* __restrict__ kvp, float* __restrict__ ksp) {
    __shared__ __align__(16) float Ks[64][64];
    __shared__ __align__(16) float Vs[64][64];
    const int c = blockIdx.x, bh = blockIdx.y;
    const int b = bh >> 4, h = bh & 15;
    const int tid = threadIdx.x;
    const int dk = tid & 63, g = tid >> 6;
    float acc[16];
#pragma unroll
    for (int j = 0; j < 16; ++j) acc[j] = 0.f;
    float ks = 0.f;
    const long rowbase = (long)b * T_ + (long)c * 256;
    const int col0 = h * 64;

    for (int s = 0; s < 4; ++s) {
        __syncthreads();
        {
            int rr = tid >> 2;
            int cc = (tid & 3) * 16;
            const long gr = rowbase + s * 64 + rr;
            const short* kp = Kb + gr * 1024 + col0 + cc;
            const short* vp = Vb + gr * 1024 + col0 + cc;
            short8 k0 = *(const short8*)(kp);
            short8 k1 = *(const short8*)(kp + 8);
            short8 v0 = *(const short8*)(vp);
            short8 v1 = *(const short8*)(vp + 8);
            float kf[16], vf[16];
#pragma unroll
            for (int e = 0; e < 8; ++e) {
                kf[e] = b2f(k0[e]); kf[8 + e] = b2f(k1[e]);
                vf[e] = b2f(v0[e]); vf[8 + e] = b2f(v1[e]);
            }
#pragma unroll
            for (int q = 0; q < 4; ++q) {
                *(f32x4*)&Ks[rr][cc + q * 4] = *(f32x4*)&kf[q * 4];
                *(f32x4*)&Vs[rr][cc + q * 4] = *(f32x4*)&vf[q * 4];
            }
        }
        __syncthreads();
#pragma unroll 8
        for (int tt = 0; tt < 64; ++tt) {
            float kv_ = Ks[tt][dk];
            if (g == 0) ks += kv_;
            f32x4 v0 = *(const f32x4*)&Vs[tt][g * 16];
            f32x4 v1 = *(const f32x4*)&Vs[tt][g * 16 + 4];
            f32x4 v2 = *(const f32x4*)&Vs[tt][g * 16 + 8];
            f32x4 v3 = *(const f32x4*)&Vs[tt][g * 16 + 12];
#pragma unroll
            for (int e = 0; e < 4; ++e) {
                acc[e] += kv_ * v0[e];  acc[4 + e] += kv_ * v1[e];
                acc[8 + e] += kv_ * v2[e]; acc[12 + e] += kv_ * v3[e];
            }
        }
    }
    float* dst = kvp + ((long)bh * 16 + c) * 4096 + dk * 64 + g * 16;
#pragma unroll
    for (int q = 0; q < 4; ++q) *(f32x4*)(dst + q * 4) = *(f32x4*)&acc[q * 4];
    if (g == 0) ksp[((long)bh * 16 + c) * 64 + dk] = ks;
}

// ---------------- reduce partials -> kvT_ext bf16 [bh][80][64] ----------------
__global__ __launch_bounds__(256) void kv_reduce(
    const float* __restrict__ kvp, const float* __restrict__ ksp,
    short* __restrict__ kvT) {
    const int bh = blockIdx.x;
    const int tid = threadIdx.x;
    for (int e = tid; e < 4096; e += 256) {
        int dk = e >> 6, dv = e & 63;
        float s = 0.f;
#pragma unroll
        for (int c = 0; c < 16; ++c) s += kvp[((long)bh * 16 + c) * 4096 + e];
        kvT[(long)bh * 5120 + dv * 64 + dk] = f2b(s);
    }
    if (tid < 64) {
        float s = 0.f;
#pragma unroll
        for (int c = 0; c < 16; ++c) s += ksp[((long)bh * 16 + c) * 64 + tid];
        kvT[(long)bh * 5120 + 64 * 64 + tid] = f2b(s);
    }
    for (int e = tid; e < 15 * 64; e += 256)
        kvT[(long)bh * 5120 + 65 * 64 + e] = 0;
}

// ---------------- attn out: out = (Q . kv) / max(Q.k_sum,1e-6) ----------------
__global__ __launch_bounds__(256) void attn_out(
    const short* __restrict__ Qb, const short* __restrict__ kvT,
    short* __restrict__ attn) {
    __shared__ __align__(16) short Qs[128 * 64];
    const int tb = blockIdx.x, bh = blockIdx.y;
    const int b = bh >> 4, h = bh & 15;
    const int tid = threadIdx.x, wave = tid >> 6, lane = tid & 63;
    const long trow0 = (long)b * T_ + (long)tb * 128;
    const int col0 = h * 64;

    const int lr = lane >> 3, lc = (lane & 7) * 8;
    const short* qsrc = Qb + (trow0 + wave * 8 + lr) * 1024 + col0 + lc;
#pragma unroll
    for (int is = 0; is < 4; ++is)
        gload16(qsrc + (long)is * 32 * 1024, Qs + is * 2048 + wave * 512);

    short8 bfr[5][2];
    const short* kvb = kvT + (long)bh * 5120;
#pragma unroll
    for (int nf = 0; nf < 5; ++nf)
#pragma unroll
        for (int kk = 0; kk < 2; ++kk)
            bfr[nf][kk] = *(const short8*)(kvb + (nf * 16 + (lane & 15)) * 64 +
                                           kk * 32 + (lane >> 4) * 8);
    __syncthreads();

#pragma unroll
    for (int tf = 0; tf < 2; ++tf) {
        short8 af[2];
        int ar = wave * 32 + tf * 16 + (lane & 15);
#pragma unroll
        for (int kk = 0; kk < 2; ++kk)
            af[kk] = *(const short8*)(Qs + ar * 64 + kk * 32 + (lane >> 4) * 8);
        f32x4 oacc[5];
#pragma unroll
        for (int nf = 0; nf < 5; ++nf) {
            oacc[nf] = (f32x4)(0.0f);
#pragma unroll
            for (int kk = 0; kk < 2; ++kk)
                oacc[nf] = __builtin_amdgcn_mfma_f32_16x16x32_bf16(
                    af[kk], bfr[nf][kk], oacc[nf], 0, 0, 0);
        }
#pragma unroll
        for (int r = 0; r < 4; ++r) {
            float nv = __shfl(oacc[4][r], lane & 48, 64);  // norm col of frag 4
            nv = fmaxf(nv, 1e-6f);
            long gm = trow0 + wave * 32 + tf * 16 + (lane >> 4) * 4 + r;
#pragma unroll
            for (int nf = 0; nf < 4; ++nf) {
                float v = oacc[nf][r] / nv;
                attn[gm * 1024 + col0 + nf * 16 + (lane & 15)] = f2b(v);
            }
        }
    }
}

// ---------------- launch ----------------
extern "C" void kernel_launch(void* const* d_in, const int* in_sizes, int n_in,
                              void* d_out, int out_size, void* d_ws, size_t ws_size,
                              hipStream_t stream) {
    const float* x = (const float*)d_in[0];
    const int* mask = (const int*)d_in[1];
    const float* Wq = (const float*)d_in[2];
    const float* Wk = (const float*)d_in[3];
    const float* Wv = (const float*)d_in[4];
    const float* Wo = (const float*)d_in[5];
    float* out = (float*)d_out;
    char* ws = (char*)d_ws;

    short* xb    = (short*)(ws);                 // 33554432 B
    short* wqkvb = (short*)(ws + 33554432);      //  6291456 B
    short* wob   = (short*)(ws + 39845888);      //  2097152 B
    short* Qb    = (short*)(ws + 41943040);      // 33554432 B
    short* Kb    = (short*)(ws + 75497472);      // 33554432 B
    short* Vb    = (short*)(ws + 109051904);     // 33554432 B
    float* kvp   = (float*)(ws + 142606336);     // 16777216 B
    float* ksp   = (float*)(ws + 159383552);     //   262144 B
    short* kvT   = (short*)(ws + 159645696);     //   655360 B
    short* attnb = xb;  // x dead after projection GEMM; reuse

    hipFuncSetAttribute((const void*)gemm1t<0>,
                        hipFuncAttributeMaxDynamicSharedMemorySize, 131072);
    hipFuncSetAttribute((const void*)gemm1t<1>,
                        hipFuncAttributeMaxDynamicSharedMemorySize, 131072);

    cvt_x<<<16384, 256, 0, stream>>>(x, xb);
    cvt_weights<<<4096, 256, 0, stream>>>(Wq, Wk, Wv, Wo, wqkvb, wob);
    gemm1t<0><<<768, 512, 131072, stream>>>(xb, wqkvb, mask, Qb, Kb, Vb, nullptr);
    kv_partial<<<dim3(16, 64), 256, 0, stream>>>(Kb, Vb, kvp, ksp);
    kv_reduce<<<64, 256, 0, stream>>>(kvp, ksp, kvT);
    attn_out<<<dim3(32, 64), 256, 0, stream>>>(Qb, kvT, attnb);
    gemm1t<1><<<256, 512, 131072, stream>>>(attnb, wob, nullptr, nullptr, nullptr,
                                            nullptr, out);
}

// Round 14
// 322.623 us; speedup vs baseline: 1.0980x; 1.0980x over previous
//
#include <hip/hip_runtime.h>
#include <hip/hip_bf16.h>
#include <stdint.h>

// LinearAttention: B=4 T=4096 D=1024 H=16 HD=64
#define T_ 4096
#define M_ 16384   // B*T

typedef __attribute__((ext_vector_type(8))) short short8;   // 8 x bf16
typedef __attribute__((ext_vector_type(4))) float f32x4;

__device__ __forceinline__ short f2b(float f) {
    __hip_bfloat16 h = __float2bfloat16(f);
    return __builtin_bit_cast(short, h);
}
__device__ __forceinline__ float b2f(short s) {
    unsigned int u = ((unsigned int)(unsigned short)s) << 16;
    return __builtin_bit_cast(float, u);
}
// async global->LDS, 16B per lane; LDS dst wave-uniform (HW adds lane*16)
__device__ __forceinline__ void gload16(const void* g, void* l) {
    __builtin_amdgcn_global_load_lds(
        (const __attribute__((address_space(1))) void*)(unsigned long long)(uintptr_t)g,
        (__attribute__((address_space(3))) void*)(unsigned int)(uintptr_t)l,
        16, 0, 0);
}

// ---------------- fp32 -> bf16 converts ----------------
__global__ __launch_bounds__(256) void cvt_x(const float* __restrict__ in,
                                             short* __restrict__ out) {
    long i = ((long)blockIdx.x * 256 + threadIdx.x) * 4;
    float4 f = *(const float4*)(in + i);
    short4 o; o.x = f2b(f.x); o.y = f2b(f.y); o.z = f2b(f.z); o.w = f2b(f.w);
    *(short4*)(out + i) = o;
}

__global__ __launch_bounds__(256) void cvt_weights(
    const float* __restrict__ Wq, const float* __restrict__ Wk,
    const float* __restrict__ Wv, const float* __restrict__ Wo,
    short* __restrict__ wqkvb, short* __restrict__ wob) {
    long i = ((long)blockIdx.x * 256 + threadIdx.x) * 4;
    int region = (int)(i >> 20);
    long off = i & 1048575;
    const float* src = region == 0 ? Wq : region == 1 ? Wk : region == 2 ? Wv : Wo;
    short* dst = region < 3 ? wqkvb + (long)region * 1048576 : wob;
    float4 f = *(const float4*)(src + off);
    short4 o; o.x = f2b(f.x); o.y = f2b(f.y); o.z = f2b(f.z); o.w = f2b(f.w);
    *(short4*)(dst + off) = o;
}

// ------- 256x256 B-DIRECT GEMM: C[M,N] = A[M,K] * Bw[N,K]^T, K=1024 ---------
// 8 waves (2M x 4N), per-wave 128x64 out. BK=64, 16 K-tiles.
// B fragments read DIRECTLY from global (L2-resident panel) into registers --
// B never touches LDS. LDS holds only A, dbuf 2 x 16384 shorts (32KB each).
// R13 BUG FIX: buffer stride was d*8192 (half a buffer!) -> buf1 overlapped
// buf0's hi rows, deterministically corrupting mm(4) operands. Now d*16384.
// LDS traffic/tile: 128KB reads + 32KB writes (~1880 cyc) < MFMA (~2070 cyc)
// -> MFMA pipe becomes the binding resource (vs R8/R11's LDS-bound ~150us).
// Register budget: single a-set (32) + b-set (32) + addr => ~120 VGPR
// + 128 acc AGPR ~= 250 <= 256 (2 waves/SIMD, no spill).
// Schedule/tile (1 barrier):
//   stageA(t+1)->dn | rdA(d,lo) 8 ds | LGKM0+SCHED0 | mm(0) 32 MFMA
//   | rdA(d,hi) 8 ds | LGKM0+SCHED0 | mm(4) 32 MFMA
//   | loadB(t+1) 8 global b128 (AFTER last b use -- R4/R5 reg-WAR lesson)
//   | VMW(8) [queue = stageA x4 oldest + B x8 -> stageA landed] | BAR | SCHED0
// Hazards: RAW fresh-A = VMW(8)->BAR->SCHED0 (queue composition verified incl.
// prologue and t=14/15 tails; compiler separately waits B-reg loads before
// use). WAR A-buf: tile t-1's rdA(dn) drains at its LGKM0s before its BAR;
// stageA(t+1)->dn issues after. XOR swizzle on A (proven, 0 conflicts).
template <int MODE>
__global__ __launch_bounds__(512) void gemm_bd(
    const short* __restrict__ A, const short* __restrict__ Bw,
    const int* __restrict__ mask,
    short* __restrict__ oQ, short* __restrict__ oK, short* __restrict__ oV,
    float* __restrict__ oF) {
    extern __shared__ short lds[];   // 32768 shorts = 64KB, A only
    const int tid = threadIdx.x;
    const int wave = tid >> 6, lane = tid & 63;
    const int wm = wave >> 2, wn = wave & 3;

    // bijective XCD swizzle (gridDim.x % 8 == 0 for both modes)
    const int nwg = gridDim.x;
    const int cpx = nwg >> 3;
    const int wg = (blockIdx.x & 7) * cpx + (blockIdx.x >> 3);
    const int bm = wg & 63, bn = wg >> 6;
    const long m0 = (long)bm * 256, n0 = (long)bn * 256;

    f32x4 acc[8][4];
#pragma unroll
    for (int i = 0; i < 8; ++i)
#pragma unroll
        for (int j = 0; j < 4; ++j) acc[i][j] = (f32x4)(0.0f);

    // A staging base: lane l covers row +(l>>3), global col-slot ((l&7)^(l>>3))
    const short* aStageBase = A + (m0 + (lane >> 3)) * 1024 +
                              (((lane & 7) ^ (lane >> 3)) * 8);
    // stage A-tile t (256 rows x 64): 4 gloads/wave; buf d = d*16384 shorts
    auto stageA = [&](int t) {
        const int d = t & 1;
#pragma unroll
        for (int j = 0; j < 4; ++j) {
            const int r = wave * 8 + j * 64;
            gload16(aStageBase + (long)r * 1024 + t * 64,
                    lds + d * 16384 + r * 64);
        }
    };

    // B fragment base (global, unswizzled): lane l -> row n0+wn*64+n*16+(l&15),
    // k-offset (l>>4)*8; frag (n,kk) at + n*16*1024 + t*64 + kk*32
    const int laneR = lane & 15;
    const short* bFragBase = Bw + (n0 + wn * 64 + laneR) * 1024 + (lane >> 4) * 8;

    short8 a[4][2], b[4][2];
    auto loadB = [&](int t) {
#pragma unroll
        for (int n = 0; n < 4; ++n) {
            b[n][0] = *(const short8*)(bFragBase + n * 16384 + t * 64);
            b[n][1] = *(const short8*)(bFragBase + n * 16384 + t * 64 + 32);
        }
    };

    // A fragment reads (swizzled LDS). Row = wm*128 + hi*64 + m*16 + laneR,
    // element offset = d*16384 + row*64 + slot; slot = sB0 (kk=0) / sB0^32.
    const int sB0 = (((lane >> 4) ^ (lane & 7)) * 8);
    auto rdA = [&](int d, int hi) {
        const int base0 = d * 16384 + wm * 8192 + hi * 4096 + laneR * 64;
#pragma unroll
        for (int m = 0; m < 4; ++m) {
            a[m][0] = *(const short8*)(lds + base0 + m * 1024 + sB0);
            a[m][1] = *(const short8*)(lds + base0 + m * 1024 + (sB0 ^ 32));
        }
    };

    auto mm = [&](int mo) {
        __builtin_amdgcn_s_setprio(1);
#pragma unroll
        for (int kk = 0; kk < 2; ++kk)
#pragma unroll
            for (int m = 0; m < 4; ++m)
#pragma unroll
                for (int n = 0; n < 4; ++n)
                    acc[mo + m][n] = __builtin_amdgcn_mfma_f32_16x16x32_bf16(
                        a[m][kk], b[n][kk], acc[mo + m][n], 0, 0, 0);
        __builtin_amdgcn_s_setprio(0);
    };

#define BAR()    __builtin_amdgcn_s_barrier()
#define LGKM0()  asm volatile("s_waitcnt lgkmcnt(0)" ::: "memory")
#define VMW8()   asm volatile("s_waitcnt vmcnt(8)" ::: "memory")
#define SCHED0() __builtin_amdgcn_sched_barrier(0)

    // -------- prologue: A(0) staged+visible, B(0) in flight --------
    stageA(0);                      // queue: [stage x4]
    loadB(0);                       // queue: [stage x4, B x8]
    VMW8();                         // stage(0) landed (oldest 4 of 12)
    BAR();                          // cross-wave visible
    SCHED0();

    for (int t = 0; t < 16; ++t) {
        const int d = t & 1;
        if (t + 1 < 16) stageA(t + 1);      // 4 gloads -> buf dn
        rdA(d, 0);                          // 8 ds_reads (lo half)
        LGKM0(); SCHED0();
        mm(0);                              // 32 MFMA (b: compiler-waited)
        rdA(d, 1);                          // 8 ds_reads (hi half)
        LGKM0(); SCHED0();
        mm(4);                              // 32 MFMA
        if (t + 1 < 16) loadB(t + 1);       // 8 global b128 (after last b use)
        VMW8();                             // stageA(t+1) landed; B in flight
        BAR();                              // cross-wave: A(t+1) visible
        SCHED0();                           // next iter's reads stay below
    }

    // ---------------- epilogue ----------------
    if (MODE == 0) {
        const int sec = (int)(n0 >> 10);        // 0=Q 1=K 2=V (uniform per block)
        short* outp = sec == 0 ? oQ : (sec == 1 ? oK : oV);
        const long cbase = n0 & 1023;
#pragma unroll
        for (int mi = 0; mi < 8; ++mi) {
#pragma unroll
            for (int r = 0; r < 4; ++r) {
                long gm = m0 + wm * 128 + mi * 16 + (lane >> 4) * 4 + r;
                int mz = (sec >= 1) ? mask[gm] : 0;
#pragma unroll
                for (int ni = 0; ni < 4; ++ni) {
                    long gn = cbase + wn * 64 + ni * 16 + (lane & 15);
                    float v = acc[mi][ni][r];
                    if (sec <= 1) v = (v > 0.f) ? v + 1.f : __expf(v);  // elu+1
                    if (mz) v = 0.f;
                    outp[gm * 1024 + gn] = f2b(v);
                }
            }
        }
    } else {
#pragma unroll
        for (int mi = 0; mi < 8; ++mi)
#pragma unroll
            for (int r = 0; r < 4; ++r) {
                long gm = m0 + wm * 128 + mi * 16 + (lane >> 4) * 4 + r;
#pragma unroll
                for (int ni = 0; ni < 4; ++ni) {
                    long gn = n0 + wn * 64 + ni * 16 + (lane & 15);
                    oF[gm * 1024 + gn] = acc[mi][ni][r];
                }
            }
    }
#undef BAR
#undef LGKM0
#undef VMW8
#undef SCHED0
}

// ---------------- kv partial: kv[bh][dk][dv] += K[t][dk]*V[t][dv] ----------------
__global__ __launch_bounds__(256) void kv_partial(
    const short* __restrict__ Kb, const short* __restrict__ Vb,
    float* __restrict__ kvp, float* __restrict__ ksp) {
    __shared__ __align__(16) float Ks[64][64];
    __shared__ __align__(16) float Vs[64][64];
    const int c = blockIdx.x, bh = blockIdx.y;
    const int b = bh >> 4, h = bh & 15;
    const int tid = threadIdx.x;
    const int dk = tid & 63, g = tid >> 6;
    float acc[16];
#pragma unroll
    for (int j = 0; j < 16; ++j) acc[j] = 0.f;
    float ks = 0.f;
    const long rowbase = (long)b * T_ + (long)c * 256;
    const int col0 = h * 64;

    for (int s = 0; s < 4; ++s) {
        __syncthreads();
        {
            int rr = tid >> 2;
            int cc = (tid & 3) * 16;
            const long gr = rowbase + s * 64 + rr;
            const short* kp = Kb + gr * 1024 + col0 + cc;
            const short* vp = Vb + gr * 1024 + col0 + cc;
            short8 k0 = *(const short8*)(kp);
            short8 k1 = *(const short8*)(kp + 8);
            short8 v0 = *(const short8*)(vp);
            short8 v1 = *(const short8*)(vp + 8);
            float kf[16], vf[16];
#pragma unroll
            for (int e = 0; e < 8; ++e) {
                kf[e] = b2f(k0[e]); kf[8 + e] = b2f(k1[e]);
                vf[e] = b2f(v0[e]); vf[8 + e] = b2f(v1[e]);
            }
#pragma unroll
            for (int q = 0; q < 4; ++q) {
                *(f32x4*)&Ks[rr][cc + q * 4] = *(f32x4*)&kf[q * 4];
                *(f32x4*)&Vs[rr][cc + q * 4] = *(f32x4*)&vf[q * 4];
            }
        }
        __syncthreads();
#pragma unroll 8
        for (int tt = 0; tt < 64; ++tt) {
            float kv_ = Ks[tt][dk];
            if (g == 0) ks += kv_;
            f32x4 v0 = *(const f32x4*)&Vs[tt][g * 16];
            f32x4 v1 = *(const f32x4*)&Vs[tt][g * 16 + 4];
            f32x4 v2 = *(const f32x4*)&Vs[tt][g * 16 + 8];
            f32x4 v3 = *(const f32x4*)&Vs[tt][g * 16 + 12];
#pragma unroll
            for (int e = 0; e < 4; ++e) {
                acc[e] += kv_ * v0[e];  acc[4 + e] += kv_ * v1[e];
                acc[8 + e] += kv_ * v2[e]; acc[12 + e] += kv_ * v3[e];
            }
        }
    }
    float* dst = kvp + ((long)bh * 16 + c) * 4096 + dk * 64 + g * 16;
#pragma unroll
    for (int q = 0; q < 4; ++q) *(f32x4*)(dst + q * 4) = *(f32x4*)&acc[q * 4];
    if (g == 0) ksp[((long)bh * 16 + c) * 64 + dk] = ks;
}

// ---------------- reduce partials -> kvT_ext bf16 [bh][80][64] ----------------
__global__ __launch_bounds__(256) void kv_reduce(
    const float* __restrict__ kvp, const float* __restrict__ ksp,
    short* __restrict__ kvT) {
    const int bh = blockIdx.x;
    const int tid = threadIdx.x;
    for (int e = tid; e < 4096; e += 256) {
        int dk = e >> 6, dv = e & 63;
        float s = 0.f;
#pragma unroll
        for (int c = 0; c < 16; ++c) s += kvp[((long)bh * 16 + c) * 4096 + e];
        kvT[(long)bh * 5120 + dv * 64 + dk] = f2b(s);
    }
    if (tid < 64) {
        float s = 0.f;
#pragma unroll
        for (int c = 0; c < 16; ++c) s += ksp[((long)bh * 16 + c) * 64 + tid];
        kvT[(long)bh * 5120 + 64 * 64 + tid] = f2b(s);
    }
    for (int e = tid; e < 15 * 64; e += 256)
        kvT[(long)bh * 5120 + 65 * 64 + e] = 0;
}

// ---------------- attn out: out = (Q . kv) / max(Q.k_sum,1e-6) ----------------
__global__ __launch_bounds__(256) void attn_out(
    const short* __restrict__ Qb, const short* __restrict__ kvT,
    short* __restrict__ attn) {
    __shared__ __align__(16) short Qs[128 * 64];
    const int tb = blockIdx.x, bh = blockIdx.y;
    const int b = bh >> 4, h = bh & 15;
    const int tid = threadIdx.x, wave = tid >> 6, lane = tid & 63;
    const long trow0 = (long)b * T_ + (long)tb * 128;
    const int col0 = h * 64;

    const int lr = lane >> 3, lc = (lane & 7) * 8;
    const short* qsrc = Qb + (trow0 + wave * 8 + lr) * 1024 + col0 + lc;
#pragma unroll
    for (int is = 0; is < 4; ++is)
        gload16(qsrc + (long)is * 32 * 1024, Qs + is * 2048 + wave * 512);

    short8 bfr[5][2];
    const short* kvb = kvT + (long)bh * 5120;
#pragma unroll
    for (int nf = 0; nf < 5; ++nf)
#pragma unroll
        for (int kk = 0; kk < 2; ++kk)
            bfr[nf][kk] = *(const short8*)(kvb + (nf * 16 + (lane & 15)) * 64 +
                                           kk * 32 + (lane >> 4) * 8);
    __syncthreads();

#pragma unroll
    for (int tf = 0; tf < 2; ++tf) {
        short8 af[2];
        int ar = wave * 32 + tf * 16 + (lane & 15);
#pragma unroll
        for (int kk = 0; kk < 2; ++kk)
            af[kk] = *(const short8*)(Qs + ar * 64 + kk * 32 + (lane >> 4) * 8);
        f32x4 oacc[5];
#pragma unroll
        for (int nf = 0; nf < 5; ++nf) {
            oacc[nf] = (f32x4)(0.0f);
#pragma unroll
            for (int kk = 0; kk < 2; ++kk)
                oacc[nf] = __builtin_amdgcn_mfma_f32_16x16x32_bf16(
                    af[kk], bfr[nf][kk], oacc[nf], 0, 0, 0);
        }
#pragma unroll
        for (int r = 0; r < 4; ++r) {
            float nv = __shfl(oacc[4][r], lane & 48, 64);  // norm col of frag 4
            nv = fmaxf(nv, 1e-6f);
            long gm = trow0 + wave * 32 + tf * 16 + (lane >> 4) * 4 + r;
#pragma unroll
            for (int nf = 0; nf < 4; ++nf) {
                float v = oacc[nf][r] / nv;
                attn[gm * 1024 + col0 + nf * 16 + (lane & 15)] = f2b(v);
            }
        }
    }
}

// ---------------- launch ----------------
extern "C" void kernel_launch(void* const* d_in, const int* in_sizes, int n_in,
                              void* d_out, int out_size, void* d_ws, size_t ws_size,
                              hipStream_t stream) {
    const float* x = (const float*)d_in[0];
    const int* mask = (const int*)d_in[1];
    const float* Wq = (const float*)d_in[2];
    const float* Wk = (const float*)d_in[3];
    const float* Wv = (const float*)d_in[4];
    const float* Wo = (const float*)d_in[5];
    float* out = (float*)d_out;
    char* ws = (char*)d_ws;

    short* xb    = (short*)(ws);                 // 33554432 B
    short* wqkvb = (short*)(ws + 33554432);      //  6291456 B
    short* wob   = (short*)(ws + 39845888);      //  2097152 B
    short* Qb    = (short*)(ws + 41943040);      // 33554432 B
    short* Kb    = (short*)(ws + 75497472);      // 33554432 B
    short* Vb    = (short*)(ws + 109051904);     // 33554432 B
    float* kvp   = (float*)(ws + 142606336);     // 16777216 B
    float* ksp   = (float*)(ws + 159383552);     //   262144 B
    short* kvT   = (short*)(ws + 159645696);     //   655360 B
    short* attnb = xb;  // x dead after projection GEMM; reuse

    hipFuncSetAttribute((const void*)gemm_bd<0>,
                        hipFuncAttributeMaxDynamicSharedMemorySize, 65536);
    hipFuncSetAttribute((const void*)gemm_bd<1>,
                        hipFuncAttributeMaxDynamicSharedMemorySize, 65536);

    cvt_x<<<16384, 256, 0, stream>>>(x, xb);
    cvt_weights<<<4096, 256, 0, stream>>>(Wq, Wk, Wv, Wo, wqkvb, wob);
    gemm_bd<0><<<768, 512, 65536, stream>>>(xb, wqkvb, mask, Qb, Kb, Vb, nullptr);
    kv_partial<<<dim3(16, 64), 256, 0, stream>>>(Kb, Vb, kvp, ksp);
    kv_reduce<<<64, 256, 0, stream>>>(kvp, ksp, kvT);
    attn_out<<<dim3(32, 64), 256, 0, stream>>>(Qb, kvT, attnb);
    gemm_bd<1><<<256, 512, 65536, stream>>>(attnb, wob, nullptr, nullptr, nullptr,
                                            nullptr, out);
}

// Round 15
// 250.111 us; speedup vs baseline: 1.4164x; 1.2899x over previous
//
#include <hip/hip_runtime.h>
#include <hip/hip_bf16.h>
#include <stdint.h>

// LinearAttention: B=4 T=4096 D=1024 H=16 HD=64
#define T_ 4096
#define M_ 16384   // B*T

typedef __attribute__((ext_vector_type(8))) short short8;   // 8 x bf16
typedef __attribute__((ext_vector_type(4))) float f32x4;

__device__ __forceinline__ short f2b(float f) {
    __hip_bfloat16 h = __float2bfloat16(f);
    return __builtin_bit_cast(short, h);
}
__device__ __forceinline__ float b2f(short s) {
    unsigned int u = ((unsigned int)(unsigned short)s) << 16;
    return __builtin_bit_cast(float, u);
}
// async global->LDS, 16B per lane; LDS dst wave-uniform (HW adds lane*16)
__device__ __forceinline__ void gload16(const void* g, void* l) {
    __builtin_amdgcn_global_load_lds(
        (const __attribute__((address_space(1))) void*)(unsigned long long)(uintptr_t)g,
        (__attribute__((address_space(3))) void*)(unsigned int)(uintptr_t)l,
        16, 0, 0);
}

// ---------------- fp32 -> bf16 converts ----------------
__global__ __launch_bounds__(256) void cvt_x(const float* __restrict__ in,
                                             short* __restrict__ out) {
    long i = ((long)blockIdx.x * 256 + threadIdx.x) * 4;
    float4 f = *(const float4*)(in + i);
    short4 o; o.x = f2b(f.x); o.y = f2b(f.y); o.z = f2b(f.z); o.w = f2b(f.w);
    *(short4*)(out + i) = o;
}

__global__ __launch_bounds__(256) void cvt_weights(
    const float* __restrict__ Wq, const float* __restrict__ Wk,
    const float* __restrict__ Wv, const float* __restrict__ Wo,
    short* __restrict__ wqkvb, short* __restrict__ wob) {
    long i = ((long)blockIdx.x * 256 + threadIdx.x) * 4;
    int region = (int)(i >> 20);
    long off = i & 1048575;
    const float* src = region == 0 ? Wq : region == 1 ? Wk : region == 2 ? Wv : Wo;
    short* dst = region < 3 ? wqkvb + (long)region * 1048576 : wob;
    float4 f = *(const float4*)(src + off);
    short4 o; o.x = f2b(f.x); o.y = f2b(f.y); o.z = f2b(f.z); o.w = f2b(f.w);
    *(short4*)(dst + off) = o;
}

// ------- 256x256 4-sub-phase GEMM: C[M,N] = A[M,K] * Bw[N,K]^T, K=1024 -------
// R11 schedule UNCHANGED (best passing: 150us MODE0). This round: L2-aware
// block decode. OLD: bm = wg&63 (fast) -> each XCD's contiguous 96-wg chunk
// walked ALL 64 A-panels (32MB through a 4MB L2 -> A staging = HBM-miss
// ~900cyc, the stall every schedule shared). NEW: bn = wg%NB (fast),
// bm = wg/NB (slow) -> per-XCD chunk touches 8 A-panels (4MB, L2-fit); B
// panels are read-shared by all XCDs and live in L3.
// Hazard invariants (unchanged from R8/R11):
//   RAW: tile-end {VMW0; BAR; SCHED0} covers next tile's reads.
//   WAR: stage into dn @P1/P2(t); dn's reads (tile t-1) drained at t-1's
//        in-phase LGKM0s, barriers in between. All waits FULL drains.
template <int MODE>
__global__ __launch_bounds__(512) void gemm4s(
    const short* __restrict__ A, const short* __restrict__ Bw,
    const int* __restrict__ mask,
    short* __restrict__ oQ, short* __restrict__ oK, short* __restrict__ oV,
    float* __restrict__ oF) {
    extern __shared__ short lds[];   // 65536 shorts = 128KB
    const int tid = threadIdx.x;
    const int wave = tid >> 6, lane = tid & 63;
    const int wm = wave >> 2, wn = wave & 3;

    // bijective XCD swizzle (gridDim.x % 8 == 0 for both modes)
    const int nwg = gridDim.x;
    const int cpx = nwg >> 3;
    const int wg = (blockIdx.x & 7) * cpx + (blockIdx.x >> 3);
    // L2-aware decode: bn fast, bm slow (A-panel footprint per XCD = 4MB)
    const int NB = (MODE == 0) ? 12 : 4;
    const int bn = wg % NB, bm = wg / NB;
    const long m0 = (long)bm * 256, n0 = (long)bn * 256;

    f32x4 acc[8][4];
#pragma unroll
    for (int i = 0; i < 8; ++i)
#pragma unroll
        for (int j = 0; j < 4; ++j) acc[i][j] = (f32x4)(0.0f);

    // staging bases: lane l covers row +(l>>3), global col-slot ((l&7)^(l>>3))
    const short* aStageBase = A + (m0 + (lane >> 3)) * 1024 +
                              (((lane & 7) ^ (lane >> 3)) * 8);
    const short* bStageBase = Bw + (n0 + (lane >> 3)) * 1024 +
                              (((lane & 7) ^ (lane >> 3)) * 8);

    // stage A-tile t (256 rows x 64): 4 gloads/wave, rows wave*8 + j*64
    auto stageA = [&](int t) {
        const int d = t & 1;
#pragma unroll
        for (int j = 0; j < 4; ++j) {
            const int r = wave * 8 + j * 64;
            gload16(aStageBase + (long)r * 1024 + t * 64, lds + d * 16384 + r * 64);
        }
    };
    auto stageB = [&](int t) {
        const int d = t & 1;
#pragma unroll
        for (int j = 0; j < 4; ++j) {
            const int r = wave * 8 + j * 64;
            gload16(bStageBase + (long)r * 1024 + t * 64,
                    lds + 32768 + d * 16384 + r * 64);
        }
    };

    // ---- hoisted DS read bases (element offsets into lds) ----
    const int laneR = lane & 15;
    const int sB0 = (((lane >> 4) ^ (lane & 7)) * 8);
    const int cA0 = wm * 8192 + laneR * 64 + sB0;              // kk=0
    const int cA1 = wm * 8192 + laneR * 64 + (sB0 ^ 32);       // kk=1
    const int cB0 = 32768 + (wn >> 1) * 8192 + (wn & 1) * 4096 +
                    laneR * 64 + sB0;
    const int cB1 = 32768 + (wn >> 1) * 8192 + (wn & 1) * 4096 +
                    laneR * 64 + (sB0 ^ 32);

    short8 alo[4][2], ahi[4][2], blo[2][2], bhi[2][2];
    auto rdAlo = [&](int pa0, int pa1) {
#pragma unroll
        for (int m = 0; m < 4; ++m) {
            alo[m][0] = *(const short8*)(lds + pa0 + m * 1024);
            alo[m][1] = *(const short8*)(lds + pa1 + m * 1024);
        }
    };
    auto rdAhi = [&](int pa0, int pa1) {
#pragma unroll
        for (int m = 0; m < 4; ++m) {
            ahi[m][0] = *(const short8*)(lds + pa0 + 4096 + m * 1024);
            ahi[m][1] = *(const short8*)(lds + pa1 + 4096 + m * 1024);
        }
    };
    auto rdBlo = [&](int pb0, int pb1) {
#pragma unroll
        for (int n = 0; n < 2; ++n) {
            blo[n][0] = *(const short8*)(lds + pb0 + n * 1024);
            blo[n][1] = *(const short8*)(lds + pb1 + n * 1024);
        }
    };
    auto rdBhi = [&](int pb0, int pb1) {
#pragma unroll
        for (int n = 0; n < 2; ++n) {
            bhi[n][0] = *(const short8*)(lds + pb0 + 2048 + n * 1024);
            bhi[n][1] = *(const short8*)(lds + pb1 + 2048 + n * 1024);
        }
    };
    // kk-OUTER: consecutive MFMAs touch different acc; same acc 8 apart.
    auto mm = [&](short8 (&a)[4][2], short8 (&b)[2][2], int mo, int no) {
        __builtin_amdgcn_s_setprio(1);
#pragma unroll
        for (int kk = 0; kk < 2; ++kk)
#pragma unroll
            for (int m = 0; m < 4; ++m)
#pragma unroll
                for (int n = 0; n < 2; ++n)
                    acc[mo + m][no + n] = __builtin_amdgcn_mfma_f32_16x16x32_bf16(
                        a[m][kk], b[n][kk], acc[mo + m][no + n], 0, 0, 0);
        __builtin_amdgcn_s_setprio(0);
    };

#define BAR()    __builtin_amdgcn_s_barrier()
#define LGKM0()  asm volatile("s_waitcnt lgkmcnt(0)" ::: "memory")
#define VMW0()   asm volatile("s_waitcnt vmcnt(0)" ::: "memory")
#define SCHED0() __builtin_amdgcn_sched_barrier(0)

    // -------- prologue: tile0 staged + visible --------
    stageA(0); stageB(0);
    VMW0();
    BAR();
    SCHED0();

#pragma unroll 2
    for (int t = 0; t < 16; ++t) {
        const int dofs = (t & 1) * 16384;
        const int pa0 = cA0 + dofs, pa1 = cA1 + dofs;
        const int pb0 = cB0 + dofs, pb1 = cB1 + dofs;
        // ---- P1: mm(alo,blo) ----
        if (t + 1 < 16) stageA(t + 1);
        rdAlo(pa0, pa1); rdBlo(pb0, pb1);   // 12 reads
        BAR(); LGKM0(); SCHED0();
        mm(alo, blo, 0, 0);
        BAR();
        // ---- P2: mm(ahi,blo) ----
        if (t + 1 < 16) stageB(t + 1);
        rdAhi(pa0, pa1);                    // 8 reads
        BAR(); LGKM0(); SCHED0();
        mm(ahi, blo, 4, 0);
        BAR();
        // ---- P3: mm(ahi,bhi) ----
        rdBhi(pb0, pb1);                    // 4 reads
        BAR(); LGKM0(); SCHED0();
        mm(ahi, bhi, 4, 2);
        BAR();
        // ---- P4: mm(alo,bhi) + tile-end drain ----
        mm(alo, bhi, 0, 2);
        VMW0();                             // stages issued P1/P2 -> queue ~empty
        BAR(); SCHED0();                    // fresh-data fence for next tile
    }

    // ---------------- epilogue ----------------
    if (MODE == 0) {
        const int sec = (int)(n0 >> 10);        // 0=Q 1=K 2=V (uniform per block)
        short* outp = sec == 0 ? oQ : (sec == 1 ? oK : oV);
        const long cbase = n0 & 1023;
#pragma unroll
        for (int mi = 0; mi < 8; ++mi) {
#pragma unroll
            for (int r = 0; r < 4; ++r) {
                long gm = m0 + wm * 128 + mi * 16 + (lane >> 4) * 4 + r;
                int mz = (sec >= 1) ? mask[gm] : 0;
#pragma unroll
                for (int ni = 0; ni < 4; ++ni) {
                    long gn = cbase + wn * 64 + ni * 16 + (lane & 15);
                    float v = acc[mi][ni][r];
                    if (sec <= 1) v = (v > 0.f) ? v + 1.f : __expf(v);  // elu+1
                    if (mz) v = 0.f;
                    outp[gm * 1024 + gn] = f2b(v);
                }
            }
        }
    } else {
#pragma unroll
        for (int mi = 0; mi < 8; ++mi)
#pragma unroll
            for (int r = 0; r < 4; ++r) {
                long gm = m0 + wm * 128 + mi * 16 + (lane >> 4) * 4 + r;
#pragma unroll
                for (int ni = 0; ni < 4; ++ni) {
                    long gn = n0 + wn * 64 + ni * 16 + (lane & 15);
                    oF[gm * 1024 + gn] = acc[mi][ni][r];
                }
            }
    }
#undef BAR
#undef LGKM0
#undef VMW0
#undef SCHED0
}

// ---------------- kv partial: kv[bh][dk][dv] += K[t][dk]*V[t][dv] ----------------
__global__ __launch_bounds__(256) void kv_partial(
    const short* __restrict__ Kb, const short* __restrict__ Vb,
    float* __restrict__ kvp, float* __restrict__ ksp) {
    __shared__ __align__(16) float Ks[64][64];
    __shared__ __align__(16) float Vs[64][64];
    const int c = blockIdx.x, bh = blockIdx.y;
    const int b = bh >> 4, h = bh & 15;
    const int tid = threadIdx.x;
    const int dk = tid & 63, g = tid >> 6;
    float acc[16];
#pragma unroll
    for (int j = 0; j < 16; ++j) acc[j] = 0.f;
    float ks = 0.f;
    const long rowbase = (long)b * T_ + (long)c * 256;
    const int col0 = h * 64;

    for (int s = 0; s < 4; ++s) {
        __syncthreads();
        {
            int rr = tid >> 2;
            int cc = (tid & 3) * 16;
            const long gr = rowbase + s * 64 + rr;
            const short* kp = Kb + gr * 1024 + col0 + cc;
            const short* vp = Vb + gr * 1024 + col0 + cc;
            short8 k0 = *(const short8*)(kp);
            short8 k1 = *(const short8*)(kp + 8);
            short8 v0 = *(const short8*)(vp);
            short8 v1 = *(const short8*)(vp + 8);
            float kf[16], vf[16];
#pragma unroll
            for (int e = 0; e < 8; ++e) {
                kf[e] = b2f(k0[e]); kf[8 + e] = b2f(k1[e]);
                vf[e] = b2f(v0[e]); vf[8 + e] = b2f(v1[e]);
            }
#pragma unroll
            for (int q = 0; q < 4; ++q) {
                *(f32x4*)&Ks[rr][cc + q * 4] = *(f32x4*)&kf[q * 4];
                *(f32x4*)&Vs[rr][cc + q * 4] = *(f32x4*)&vf[q * 4];
            }
        }
        __syncthreads();
#pragma unroll 8
        for (int tt = 0; tt < 64; ++tt) {
            float kv_ = Ks[tt][dk];
            if (g == 0) ks += kv_;
            f32x4 v0 = *(const f32x4*)&Vs[tt][g * 16];
            f32x4 v1 = *(const f32x4*)&Vs[tt][g * 16 + 4];
            f32x4 v2 = *(const f32x4*)&Vs[tt][g * 16 + 8];
            f32x4 v3 = *(const f32x4*)&Vs[tt][g * 16 + 12];
#pragma unroll
            for (int e = 0; e < 4; ++e) {
                acc[e] += kv_ * v0[e];  acc[4 + e] += kv_ * v1[e];
                acc[8 + e] += kv_ * v2[e]; acc[12 + e] += kv_ * v3[e];
            }
        }
    }
    float* dst = kvp + ((long)bh * 16 + c) * 4096 + dk * 64 + g * 16;
#pragma unroll
    for (int q = 0; q < 4; ++q) *(f32x4*)(dst + q * 4) = *(f32x4*)&acc[q * 4];
    if (g == 0) ksp[((long)bh * 16 + c) * 64 + dk] = ks;
}

// ---------------- reduce partials -> kvT_ext bf16 [bh][80][64] ----------------
__global__ __launch_bounds__(256) void kv_reduce(
    const float* __restrict__ kvp, const float* __restrict__ ksp,
    short* __restrict__ kvT) {
    const int bh = blockIdx.x;
    const int tid = threadIdx.x;
    for (int e = tid; e < 4096; e += 256) {
        int dk = e >> 6, dv = e & 63;
        float s = 0.f;
#pragma unroll
        for (int c = 0; c < 16; ++c) s += kvp[((long)bh * 16 + c) * 4096 + e];
        kvT[(long)bh * 5120 + dv * 64 + dk] = f2b(s);
    }
    if (tid < 64) {
        float s = 0.f;
#pragma unroll
        for (int c = 0; c < 16; ++c) s += ksp[((long)bh * 16 + c) * 64 + tid];
        kvT[(long)bh * 5120 + 64 * 64 + tid] = f2b(s);
    }
    for (int e = tid; e < 15 * 64; e += 256)
        kvT[(long)bh * 5120 + 65 * 64 + e] = 0;
}

// ---------------- attn out: out = (Q . kv) / max(Q.k_sum,1e-6) ----------------
__global__ __launch_bounds__(256) void attn_out(
    const short* __restrict__ Qb, const short* __restrict__ kvT,
    short* __restrict__ attn) {
    __shared__ __align__(16) short Qs[128 * 64];
    const int tb = blockIdx.x, bh = blockIdx.y;
    const int b = bh >> 4, h = bh & 15;
    const int tid = threadIdx.x, wave = tid >> 6, lane = tid & 63;
    const long trow0 = (long)b * T_ + (long)tb * 128;
    const int col0 = h * 64;

    const int lr = lane >> 3, lc = (lane & 7) * 8;
    const short* qsrc = Qb + (trow0 + wave * 8 + lr) * 1024 + col0 + lc;
#pragma unroll
    for (int is = 0; is < 4; ++is)
        gload16(qsrc + (long)is * 32 * 1024, Qs + is * 2048 + wave * 512);

    short8 bfr[5][2];
    const short* kvb = kvT + (long)bh * 5120;
#pragma unroll
    for (int nf = 0; nf < 5; ++nf)
#pragma unroll
        for (int kk = 0; kk < 2; ++kk)
            bfr[nf][kk] = *(const short8*)(kvb + (nf * 16 + (lane & 15)) * 64 +
                                           kk * 32 + (lane >> 4) * 8);
    __syncthreads();

#pragma unroll
    for (int tf = 0; tf < 2; ++tf) {
        short8 af[2];
        int ar = wave * 32 + tf * 16 + (lane & 15);
#pragma unroll
        for (int kk = 0; kk < 2; ++kk)
            af[kk] = *(const short8*)(Qs + ar * 64 + kk * 32 + (lane >> 4) * 8);
        f32x4 oacc[5];
#pragma unroll
        for (int nf = 0; nf < 5; ++nf) {
            oacc[nf] = (f32x4)(0.0f);
#pragma unroll
            for (int kk = 0; kk < 2; ++kk)
                oacc[nf] = __builtin_amdgcn_mfma_f32_16x16x32_bf16(
                    af[kk], bfr[nf][kk], oacc[nf], 0, 0, 0);
        }
#pragma unroll
        for (int r = 0; r < 4; ++r) {
            float nv = __shfl(oacc[4][r], lane & 48, 64);  // norm col of frag 4
            nv = fmaxf(nv, 1e-6f);
            long gm = trow0 + wave * 32 + tf * 16 + (lane >> 4) * 4 + r;
#pragma unroll
            for (int nf = 0; nf < 4; ++nf) {
                float v = oacc[nf][r] / nv;
                attn[gm * 1024 + col0 + nf * 16 + (lane & 15)] = f2b(v);
            }
        }
    }
}

// ---------------- launch ----------------
extern "C" void kernel_launch(void* const* d_in, const int* in_sizes, int n_in,
                              void* d_out, int out_size, void* d_ws, size_t ws_size,
                              hipStream_t stream) {
    const float* x = (const float*)d_in[0];
    const int* mask = (const int*)d_in[1];
    const float* Wq = (const float*)d_in[2];
    const float* Wk = (const float*)d_in[3];
    const float* Wv = (const float*)d_in[4];
    const float* Wo = (const float*)d_in[5];
    float* out = (float*)d_out;
    char* ws = (char*)d_ws;

    short* xb    = (short*)(ws);                 // 33554432 B
    short* wqkvb = (short*)(ws + 33554432);      //  6291456 B
    short* wob   = (short*)(ws + 39845888);      //  2097152 B
    short* Qb    = (short*)(ws + 41943040);      // 33554432 B
    short* Kb    = (short*)(ws + 75497472);      // 33554432 B
    short* Vb    = (short*)(ws + 109051904);     // 33554432 B
    float* kvp   = (float*)(ws + 142606336);     // 16777216 B
    float* ksp   = (float*)(ws + 159383552);     //   262144 B
    short* kvT   = (short*)(ws + 159645696);     //   655360 B
    short* attnb = xb;  // x dead after projection GEMM; reuse

    hipFuncSetAttribute((const void*)gemm4s<0>,
                        hipFuncAttributeMaxDynamicSharedMemorySize, 131072);
    hipFuncSetAttribute((const void*)gemm4s<1>,
                        hipFuncAttributeMaxDynamicSharedMemorySize, 131072);

    cvt_x<<<16384, 256, 0, stream>>>(x, xb);
    cvt_weights<<<4096, 256, 0, stream>>>(Wq, Wk, Wv, Wo, wqkvb, wob);
    gemm4s<0><<<768, 512, 131072, stream>>>(xb, wqkvb, mask, Qb, Kb, Vb, nullptr);
    kv_partial<<<dim3(16, 64), 256, 0, stream>>>(Kb, Vb, kvp, ksp);
    kv_reduce<<<64, 256, 0, stream>>>(kvp, ksp, kvT);
    attn_out<<<dim3(32, 64), 256, 0, stream>>>(Qb, kvT, attnb);
    gemm4s<1><<<256, 512, 131072, stream>>>(attnb, wob, nullptr, nullptr, nullptr,
                                            nullptr, out);
}

// Round 16
// 225.580 us; speedup vs baseline: 1.5704x; 1.1087x over previous
//
#include <hip/hip_runtime.h>
#include <hip/hip_bf16.h>
#include <stdint.h>

// LinearAttention: B=4 T=4096 D=1024 H=16 HD=64
#define T_ 4096
#define M_ 16384   // B*T

typedef __attribute__((ext_vector_type(8))) short short8;   // 8 x bf16
typedef __attribute__((ext_vector_type(4))) float f32x4;

__device__ __forceinline__ short f2b(float f) {
    __hip_bfloat16 h = __float2bfloat16(f);
    return __builtin_bit_cast(short, h);
}
__device__ __forceinline__ float b2f(short s) {
    unsigned int u = ((unsigned int)(unsigned short)s) << 16;
    return __builtin_bit_cast(float, u);
}
// async global->LDS, 16B per lane; LDS dst wave-uniform (HW adds lane*16)
__device__ __forceinline__ void gload16(const void* g, void* l) {
    __builtin_amdgcn_global_load_lds(
        (const __attribute__((address_space(1))) void*)(unsigned long long)(uintptr_t)g,
        (__attribute__((address_space(3))) void*)(unsigned int)(uintptr_t)l,
        16, 0, 0);
}

// ---------------- fused fp32 -> bf16 converts (x + all weights) ----------------
__global__ __launch_bounds__(256) void cvt_all(
    const float* __restrict__ x,
    const float* __restrict__ Wq, const float* __restrict__ Wk,
    const float* __restrict__ Wv, const float* __restrict__ Wo,
    short* __restrict__ xb, short* __restrict__ wqkvb, short* __restrict__ wob) {
    if (blockIdx.x < 16384) {
        long i = ((long)blockIdx.x * 256 + threadIdx.x) * 4;
        float4 f = *(const float4*)(x + i);
        short4 o; o.x = f2b(f.x); o.y = f2b(f.y); o.z = f2b(f.z); o.w = f2b(f.w);
        *(short4*)(xb + i) = o;
    } else {
        long i = ((long)(blockIdx.x - 16384) * 256 + threadIdx.x) * 4;
        int region = (int)(i >> 20);
        long off = i & 1048575;
        const float* src = region == 0 ? Wq : region == 1 ? Wk
                                            : region == 2 ? Wv : Wo;
        short* dst = region < 3 ? wqkvb + (long)region * 1048576 : wob;
        float4 f = *(const float4*)(src + off);
        short4 o; o.x = f2b(f.x); o.y = f2b(f.y); o.z = f2b(f.z); o.w = f2b(f.w);
        *(short4*)(dst + off) = o;
    }
}

// ------- 256x256 4-sub-phase GEMM: C[M,N] = A[M,K] * Bw[N,K]^T, K=1024 -------
// R15 kernel UNCHANGED (best passing: 147us MODE0, FETCH 94MB, 0 conflicts).
template <int MODE>
__global__ __launch_bounds__(512) void gemm4s(
    const short* __restrict__ A, const short* __restrict__ Bw,
    const int* __restrict__ mask,
    short* __restrict__ oQ, short* __restrict__ oK, short* __restrict__ oV,
    float* __restrict__ oF) {
    extern __shared__ short lds[];   // 65536 shorts = 128KB
    const int tid = threadIdx.x;
    const int wave = tid >> 6, lane = tid & 63;
    const int wm = wave >> 2, wn = wave & 3;

    // bijective XCD swizzle (gridDim.x % 8 == 0 for both modes)
    const int nwg = gridDim.x;
    const int cpx = nwg >> 3;
    const int wg = (blockIdx.x & 7) * cpx + (blockIdx.x >> 3);
    // L2-aware decode: bn fast, bm slow (A-panel footprint per XCD = 4MB)
    const int NB = (MODE == 0) ? 12 : 4;
    const int bn = wg % NB, bm = wg / NB;
    const long m0 = (long)bm * 256, n0 = (long)bn * 256;

    f32x4 acc[8][4];
#pragma unroll
    for (int i = 0; i < 8; ++i)
#pragma unroll
        for (int j = 0; j < 4; ++j) acc[i][j] = (f32x4)(0.0f);

    // staging bases: lane l covers row +(l>>3), global col-slot ((l&7)^(l>>3))
    const short* aStageBase = A + (m0 + (lane >> 3)) * 1024 +
                              (((lane & 7) ^ (lane >> 3)) * 8);
    const short* bStageBase = Bw + (n0 + (lane >> 3)) * 1024 +
                              (((lane & 7) ^ (lane >> 3)) * 8);

    auto stageA = [&](int t) {
        const int d = t & 1;
#pragma unroll
        for (int j = 0; j < 4; ++j) {
            const int r = wave * 8 + j * 64;
            gload16(aStageBase + (long)r * 1024 + t * 64, lds + d * 16384 + r * 64);
        }
    };
    auto stageB = [&](int t) {
        const int d = t & 1;
#pragma unroll
        for (int j = 0; j < 4; ++j) {
            const int r = wave * 8 + j * 64;
            gload16(bStageBase + (long)r * 1024 + t * 64,
                    lds + 32768 + d * 16384 + r * 64);
        }
    };

    // ---- hoisted DS read bases (element offsets into lds) ----
    const int laneR = lane & 15;
    const int sB0 = (((lane >> 4) ^ (lane & 7)) * 8);
    const int cA0 = wm * 8192 + laneR * 64 + sB0;              // kk=0
    const int cA1 = wm * 8192 + laneR * 64 + (sB0 ^ 32);       // kk=1
    const int cB0 = 32768 + (wn >> 1) * 8192 + (wn & 1) * 4096 +
                    laneR * 64 + sB0;
    const int cB1 = 32768 + (wn >> 1) * 8192 + (wn & 1) * 4096 +
                    laneR * 64 + (sB0 ^ 32);

    short8 alo[4][2], ahi[4][2], blo[2][2], bhi[2][2];
    auto rdAlo = [&](int pa0, int pa1) {
#pragma unroll
        for (int m = 0; m < 4; ++m) {
            alo[m][0] = *(const short8*)(lds + pa0 + m * 1024);
            alo[m][1] = *(const short8*)(lds + pa1 + m * 1024);
        }
    };
    auto rdAhi = [&](int pa0, int pa1) {
#pragma unroll
        for (int m = 0; m < 4; ++m) {
            ahi[m][0] = *(const short8*)(lds + pa0 + 4096 + m * 1024);
            ahi[m][1] = *(const short8*)(lds + pa1 + 4096 + m * 1024);
        }
    };
    auto rdBlo = [&](int pb0, int pb1) {
#pragma unroll
        for (int n = 0; n < 2; ++n) {
            blo[n][0] = *(const short8*)(lds + pb0 + n * 1024);
            blo[n][1] = *(const short8*)(lds + pb1 + n * 1024);
        }
    };
    auto rdBhi = [&](int pb0, int pb1) {
#pragma unroll
        for (int n = 0; n < 2; ++n) {
            bhi[n][0] = *(const short8*)(lds + pb0 + 2048 + n * 1024);
            bhi[n][1] = *(const short8*)(lds + pb1 + 2048 + n * 1024);
        }
    };
    // kk-OUTER: consecutive MFMAs touch different acc; same acc 8 apart.
    auto mm = [&](short8 (&a)[4][2], short8 (&b)[2][2], int mo, int no) {
        __builtin_amdgcn_s_setprio(1);
#pragma unroll
        for (int kk = 0; kk < 2; ++kk)
#pragma unroll
            for (int m = 0; m < 4; ++m)
#pragma unroll
                for (int n = 0; n < 2; ++n)
                    acc[mo + m][no + n] = __builtin_amdgcn_mfma_f32_16x16x32_bf16(
                        a[m][kk], b[n][kk], acc[mo + m][no + n], 0, 0, 0);
        __builtin_amdgcn_s_setprio(0);
    };

#define BAR()    __builtin_amdgcn_s_barrier()
#define LGKM0()  asm volatile("s_waitcnt lgkmcnt(0)" ::: "memory")
#define VMW0()   asm volatile("s_waitcnt vmcnt(0)" ::: "memory")
#define SCHED0() __builtin_amdgcn_sched_barrier(0)

    // -------- prologue: tile0 staged + visible --------
    stageA(0); stageB(0);
    VMW0();
    BAR();
    SCHED0();

#pragma unroll 2
    for (int t = 0; t < 16; ++t) {
        const int dofs = (t & 1) * 16384;
        const int pa0 = cA0 + dofs, pa1 = cA1 + dofs;
        const int pb0 = cB0 + dofs, pb1 = cB1 + dofs;
        // ---- P1: mm(alo,blo) ----
        if (t + 1 < 16) stageA(t + 1);
        rdAlo(pa0, pa1); rdBlo(pb0, pb1);   // 12 reads
        BAR(); LGKM0(); SCHED0();
        mm(alo, blo, 0, 0);
        BAR();
        // ---- P2: mm(ahi,blo) ----
        if (t + 1 < 16) stageB(t + 1);
        rdAhi(pa0, pa1);                    // 8 reads
        BAR(); LGKM0(); SCHED0();
        mm(ahi, blo, 4, 0);
        BAR();
        // ---- P3: mm(ahi,bhi) ----
        rdBhi(pb0, pb1);                    // 4 reads
        BAR(); LGKM0(); SCHED0();
        mm(ahi, bhi, 4, 2);
        BAR();
        // ---- P4: mm(alo,bhi) + tile-end drain ----
        mm(alo, bhi, 0, 2);
        VMW0();                             // stages issued P1/P2 -> queue ~empty
        BAR(); SCHED0();                    // fresh-data fence for next tile
    }

    // ---------------- epilogue ----------------
    if (MODE == 0) {
        const int sec = (int)(n0 >> 10);        // 0=Q 1=K 2=V (uniform per block)
        short* outp = sec == 0 ? oQ : (sec == 1 ? oK : oV);
        const long cbase = n0 & 1023;
#pragma unroll
        for (int mi = 0; mi < 8; ++mi) {
#pragma unroll
            for (int r = 0; r < 4; ++r) {
                long gm = m0 + wm * 128 + mi * 16 + (lane >> 4) * 4 + r;
                int mz = (sec >= 1) ? mask[gm] : 0;
#pragma unroll
                for (int ni = 0; ni < 4; ++ni) {
                    long gn = cbase + wn * 64 + ni * 16 + (lane & 15);
                    float v = acc[mi][ni][r];
                    if (sec <= 1) v = (v > 0.f) ? v + 1.f : __expf(v);  // elu+1
                    if (mz) v = 0.f;
                    outp[gm * 1024 + gn] = f2b(v);
                }
            }
        }
    } else {
#pragma unroll
        for (int mi = 0; mi < 8; ++mi)
#pragma unroll
            for (int r = 0; r < 4; ++r) {
                long gm = m0 + wm * 128 + mi * 16 + (lane >> 4) * 4 + r;
#pragma unroll
                for (int ni = 0; ni < 4; ++ni) {
                    long gn = n0 + wn * 64 + ni * 16 + (lane & 15);
                    oF[gm * 1024 + gn] = acc[mi][ni][r];
                }
            }
    }
#undef BAR
#undef LGKM0
#undef VMW0
#undef SCHED0
}

// ------- kv via MFMA: kv[bh][dk][dv] = sum_t K[t][dk]*V[t][dv] (per chunk) ----
// grid (16 chunks, 64 bh), 256 threads (4 waves). K,V chunks transpose-staged
// into LDS as [d][256 t] bf16 with XOR t-slot swizzle:
//   write: tp = (t&7) | (((t>>3) ^ (col&7)) << 3)
//   read : slot = (ts*4 + (lane>>4)) ^ (row&7)  -> 8 contiguous shorts =
//          t-window ts*32+(lane>>4)*8 .. +7 of that row (verified bijective).
// MFMA frags use the session-proven conventions (same as gemm4s):
//   A row=lane&15 (dk), k-slice (lane>>4)*8 from Kt; B col=lane&15 (dv) from
//   Vt; C col=lane&15, row=(lane>>4)*4+r. ks = row-sums of Kt (order-free, so
//   swizzle-invariant). Replaces the VALU-loop kv_partial (~2.5x less work).
__global__ __launch_bounds__(256) void kv_mfma(
    const short* __restrict__ Kb, const short* __restrict__ Vb,
    float* __restrict__ kvp, float* __restrict__ ksp) {
    __shared__ __align__(16) short Kt[64 * 256];
    __shared__ __align__(16) short Vt[64 * 256];
    __shared__ float ksred[256];
    const int c = blockIdx.x, bh = blockIdx.y;
    const int b = bh >> 4, h = bh & 15;
    const int tid = threadIdx.x, wave = tid >> 6, lane = tid & 63;
    const long rowbase = (long)b * T_ + (long)c * 256;
    const int col0 = h * 64;

    // transpose-stage: thread handles 8 chunks of (1 row x 8 cols)
    for (int e = 0; e < 8; ++e) {
        int chunk = tid + e * 256;          // 0..2047
        int trow = chunk >> 3;              // 0..255
        int c8 = (chunk & 7) * 8;           // col offset 0,8,..,56
        short8 kv8 = *(const short8*)(Kb + (rowbase + trow) * 1024 + col0 + c8);
        short8 vv8 = *(const short8*)(Vb + (rowbase + trow) * 1024 + col0 + c8);
#pragma unroll
        for (int j = 0; j < 8; ++j) {
            int col = c8 + j;
            int tp = (trow & 7) | ((((trow >> 3) ^ (col & 7)) & 31) << 3);
            Kt[col * 256 + tp] = kv8[j];
            Vt[col * 256 + tp] = vv8[j];
        }
    }
    __syncthreads();

    const int lr = lane & 15, lk = lane >> 4;
    f32x4 acc[4];
#pragma unroll
    for (int m = 0; m < 4; ++m) acc[m] = (f32x4)(0.0f);
    for (int ts = 0; ts < 8; ++ts) {
        short8 bf;
        {
            int row = wave * 16 + lr;
            int slot = ((ts * 4 + lk) ^ (row & 7)) & 31;
            bf = *(const short8*)(Vt + row * 256 + slot * 8);
        }
#pragma unroll
        for (int m = 0; m < 4; ++m) {
            int row = m * 16 + lr;
            int slot = ((ts * 4 + lk) ^ (row & 7)) & 31;
            short8 af = *(const short8*)(Kt + row * 256 + slot * 8);
            acc[m] = __builtin_amdgcn_mfma_f32_16x16x32_bf16(af, bf, acc[m], 0, 0, 0);
        }
    }

    // ks partial: thread (dk = tid&63, quarter q = tid>>6) sums 64 elems of
    // row dk (any order -- swizzle is bijective per row).
    {
        int dk = tid & 63, q = tid >> 6;
        float s = 0.f;
#pragma unroll
        for (int j = 0; j < 8; ++j) {
            short8 v = *(const short8*)(Kt + dk * 256 + q * 64 + j * 8);
#pragma unroll
            for (int e2 = 0; e2 < 8; ++e2) s += b2f(v[e2]);
        }
        ksred[tid] = s;
    }
    __syncthreads();

    float* dst = kvp + ((long)bh * 16 + c) * 4096;
#pragma unroll
    for (int m = 0; m < 4; ++m)
#pragma unroll
        for (int r = 0; r < 4; ++r) {
            int dk = m * 16 + lk * 4 + r;
            dst[dk * 64 + wave * 16 + lr] = acc[m][r];
        }
    if (tid < 64) {
        float s = ksred[tid] + ksred[tid + 64] + ksred[tid + 128] + ksred[tid + 192];
        ksp[((long)bh * 16 + c) * 64 + tid] = s;
    }
}

// ---------------- reduce partials -> kvT_ext bf16 [bh][80][64] ----------------
__global__ __launch_bounds__(256) void kv_reduce(
    const float* __restrict__ kvp, const float* __restrict__ ksp,
    short* __restrict__ kvT) {
    const int bh = blockIdx.x;
    const int tid = threadIdx.x;
    for (int e = tid; e < 4096; e += 256) {
        int dk = e >> 6, dv = e & 63;
        float s = 0.f;
#pragma unroll
        for (int c = 0; c < 16; ++c) s += kvp[((long)bh * 16 + c) * 4096 + e];
        kvT[(long)bh * 5120 + dv * 64 + dk] = f2b(s);
    }
    if (tid < 64) {
        float s = 0.f;
#pragma unroll
        for (int c = 0; c < 16; ++c) s += ksp[((long)bh * 16 + c) * 64 + tid];
        kvT[(long)bh * 5120 + 64 * 64 + tid] = f2b(s);
    }
    for (int e = tid; e < 15 * 64; e += 256)
        kvT[(long)bh * 5120 + 65 * 64 + e] = 0;
}

// ---------------- attn out: out = (Q . kv) / max(Q.k_sum,1e-6) ----------------
__global__ __launch_bounds__(256) void attn_out(
    const short* __restrict__ Qb, const short* __restrict__ kvT,
    short* __restrict__ attn) {
    __shared__ __align__(16) short Qs[128 * 64];
    const int tb = blockIdx.x, bh = blockIdx.y;
    const int b = bh >> 4, h = bh & 15;
    const int tid = threadIdx.x, wave = tid >> 6, lane = tid & 63;
    const long trow0 = (long)b * T_ + (long)tb * 128;
    const int col0 = h * 64;

    const int lr = lane >> 3, lc = (lane & 7) * 8;
    const short* qsrc = Qb + (trow0 + wave * 8 + lr) * 1024 + col0 + lc;
#pragma unroll
    for (int is = 0; is < 4; ++is)
        gload16(qsrc + (long)is * 32 * 1024, Qs + is * 2048 + wave * 512);

    short8 bfr[5][2];
    const short* kvb = kvT + (long)bh * 5120;
#pragma unroll
    for (int nf = 0; nf < 5; ++nf)
#pragma unroll
        for (int kk = 0; kk < 2; ++kk)
            bfr[nf][kk] = *(const short8*)(kvb + (nf * 16 + (lane & 15)) * 64 +
                                           kk * 32 + (lane >> 4) * 8);
    __syncthreads();

#pragma unroll
    for (int tf = 0; tf < 2; ++tf) {
        short8 af[2];
        int ar = wave * 32 + tf * 16 + (lane & 15);
#pragma unroll
        for (int kk = 0; kk < 2; ++kk)
            af[kk] = *(const short8*)(Qs + ar * 64 + kk * 32 + (lane >> 4) * 8);
        f32x4 oacc[5];
#pragma unroll
        for (int nf = 0; nf < 5; ++nf) {
            oacc[nf] = (f32x4)(0.0f);
#pragma unroll
            for (int kk = 0; kk < 2; ++kk)
                oacc[nf] = __builtin_amdgcn_mfma_f32_16x16x32_bf16(
                    af[kk], bfr[nf][kk], oacc[nf], 0, 0, 0);
        }
#pragma unroll
        for (int r = 0; r < 4; ++r) {
            float nv = __shfl(oacc[4][r], lane & 48, 64);  // norm col of frag 4
            nv = fmaxf(nv, 1e-6f);
            long gm = trow0 + wave * 32 + tf * 16 + (lane >> 4) * 4 + r;
#pragma unroll
            for (int nf = 0; nf < 4; ++nf) {
                float v = oacc[nf][r] / nv;
                attn[gm * 1024 + col0 + nf * 16 + (lane & 15)] = f2b(v);
            }
        }
    }
}

// ---------------- launch ----------------
extern "C" void kernel_launch(void* const* d_in, const int* in_sizes, int n_in,
                              void* d_out, int out_size, void* d_ws, size_t ws_size,
                              hipStream_t stream) {
    const float* x = (const float*)d_in[0];
    const int* mask = (const int*)d_in[1];
    const float* Wq = (const float*)d_in[2];
    const float* Wk = (const float*)d_in[3];
    const float* Wv = (const float*)d_in[4];
    const float* Wo = (const float*)d_in[5];
    float* out = (float*)d_out;
    char* ws = (char*)d_ws;

    short* xb    = (short*)(ws);                 // 33554432 B
    short* wqkvb = (short*)(ws + 33554432);      //  6291456 B
    short* wob   = (short*)(ws + 39845888);      //  2097152 B
    short* Qb    = (short*)(ws + 41943040);      // 33554432 B
    short* Kb    = (short*)(ws + 75497472);      // 33554432 B
    short* Vb    = (short*)(ws + 109051904);     // 33554432 B
    float* kvp   = (float*)(ws + 142606336);     // 16777216 B
    float* ksp   = (float*)(ws + 159383552);     //   262144 B
    short* kvT   = (short*)(ws + 159645696);     //   655360 B
    short* attnb = xb;  // x dead after projection GEMM; reuse

    hipFuncSetAttribute((const void*)gemm4s<0>,
                        hipFuncAttributeMaxDynamicSharedMemorySize, 131072);
    hipFuncSetAttribute((const void*)gemm4s<1>,
                        hipFuncAttributeMaxDynamicSharedMemorySize, 131072);

    cvt_all<<<20480, 256, 0, stream>>>(x, Wq, Wk, Wv, Wo, xb, wqkvb, wob);
    gemm4s<0><<<768, 512, 131072, stream>>>(xb, wqkvb, mask, Qb, Kb, Vb, nullptr);
    kv_mfma<<<dim3(16, 64), 256, 0, stream>>>(Kb, Vb, kvp, ksp);
    kv_reduce<<<64, 256, 0, stream>>>(kvp, ksp, kvT);
    attn_out<<<dim3(32, 64), 256, 0, stream>>>(Qb, kvT, attnb);
    gemm4s<1><<<256, 512, 131072, stream>>>(attnb, wob, nullptr, nullptr, nullptr,
                                            nullptr, out);
}

// Round 17
// 213.252 us; speedup vs baseline: 1.6612x; 1.0578x over previous
//
#include <hip/hip_runtime.h>
#include <hip/hip_bf16.h>
#include <stdint.h>

// LinearAttention: B=4 T=4096 D=1024 H=16 HD=64
#define T_ 4096
#define M_ 16384   // B*T

typedef __attribute__((ext_vector_type(8))) short short8;   // 8 x bf16
typedef __attribute__((ext_vector_type(4))) float f32x4;

__device__ __forceinline__ short f2b(float f) {
    __hip_bfloat16 h = __float2bfloat16(f);
    return __builtin_bit_cast(short, h);
}
__device__ __forceinline__ float b2f(short s) {
    unsigned int u = ((unsigned int)(unsigned short)s) << 16;
    return __builtin_bit_cast(float, u);
}
// async global->LDS, 16B per lane; LDS dst wave-uniform (HW adds lane*16)
__device__ __forceinline__ void gload16(const void* g, void* l) {
    __builtin_amdgcn_global_load_lds(
        (const __attribute__((address_space(1))) void*)(unsigned long long)(uintptr_t)g,
        (__attribute__((address_space(3))) void*)(unsigned int)(uintptr_t)l,
        16, 0, 0);
}

// ---------------- fused fp32 -> bf16 converts (x + all weights) ----------------
__global__ __launch_bounds__(256) void cvt_all(
    const float* __restrict__ x,
    const float* __restrict__ Wq, const float* __restrict__ Wk,
    const float* __restrict__ Wv, const float* __restrict__ Wo,
    short* __restrict__ xb, short* __restrict__ wqkvb, short* __restrict__ wob) {
    if (blockIdx.x < 16384) {
        long i = ((long)blockIdx.x * 256 + threadIdx.x) * 4;
        float4 f = *(const float4*)(x + i);
        short4 o; o.x = f2b(f.x); o.y = f2b(f.y); o.z = f2b(f.z); o.w = f2b(f.w);
        *(short4*)(xb + i) = o;
    } else {
        long i = ((long)(blockIdx.x - 16384) * 256 + threadIdx.x) * 4;
        int region = (int)(i >> 20);
        long off = i & 1048575;
        const float* src = region == 0 ? Wq : region == 1 ? Wk
                                            : region == 2 ? Wv : Wo;
        short* dst = region < 3 ? wqkvb + (long)region * 1048576 : wob;
        float4 f = *(const float4*)(src + off);
        short4 o; o.x = f2b(f.x); o.y = f2b(f.y); o.z = f2b(f.z); o.w = f2b(f.w);
        *(short4*)(dst + off) = o;
    }
}

// ------- 256x256 GEMM, ONE BARRIER PER K-TILE: C = A[M,K]*Bw[N,K]^T, K=1024 --
// R15/R16 kernel with the 7 intra-tile barriers REMOVED (1 barrier per tile).
// Rationale: lockstep windows serialize LDS (2816cyc) + MFMA (2483cyc) pipes;
// with one barrier, waves slip across quadrant phases so one wave's MFMA
// overlaps another's LDS drain (R6/m114 mechanism) while quadrant-sequential
// reads keep live ranges short (no R12-style spill).
// Hazard audit (1-barrier invariants):
//   WAR: each wave's ALL ds_reads of buf d drain at its per-phase LGKM0s
//        BEFORE that wave reaches the tile-end BAR; stage into that parity
//        happens only after the BAR. Cross-wave safe.
//   RAW: VMW0 (own stages landed) -> BAR -> SCHED0 precedes next tile's reads.
//   LGKM0 does NOT wait on global_load_lds (vmcnt) -> stages stay in flight
//        across phases; vmcnt drained once per tile at P4.
//   Reg: each quadrant's frags are read then consumed before re-read (R4/R5).
template <int MODE>
__global__ __launch_bounds__(512) void gemm4s(
    const short* __restrict__ A, const short* __restrict__ Bw,
    const int* __restrict__ mask,
    short* __restrict__ oQ, short* __restrict__ oK, short* __restrict__ oV,
    float* __restrict__ oF) {
    extern __shared__ short lds[];   // 65536 shorts = 128KB
    const int tid = threadIdx.x;
    const int wave = tid >> 6, lane = tid & 63;
    const int wm = wave >> 2, wn = wave & 3;

    // bijective XCD swizzle (gridDim.x % 8 == 0 for both modes)
    const int nwg = gridDim.x;
    const int cpx = nwg >> 3;
    const int wg = (blockIdx.x & 7) * cpx + (blockIdx.x >> 3);
    // L2-aware decode: bn fast, bm slow (A-panel footprint per XCD = 4MB)
    const int NB = (MODE == 0) ? 12 : 4;
    const int bn = wg % NB, bm = wg / NB;
    const long m0 = (long)bm * 256, n0 = (long)bn * 256;

    f32x4 acc[8][4];
#pragma unroll
    for (int i = 0; i < 8; ++i)
#pragma unroll
        for (int j = 0; j < 4; ++j) acc[i][j] = (f32x4)(0.0f);

    // staging bases: lane l covers row +(l>>3), global col-slot ((l&7)^(l>>3))
    const short* aStageBase = A + (m0 + (lane >> 3)) * 1024 +
                              (((lane & 7) ^ (lane >> 3)) * 8);
    const short* bStageBase = Bw + (n0 + (lane >> 3)) * 1024 +
                              (((lane & 7) ^ (lane >> 3)) * 8);

    auto stageA = [&](int t) {
        const int d = t & 1;
#pragma unroll
        for (int j = 0; j < 4; ++j) {
            const int r = wave * 8 + j * 64;
            gload16(aStageBase + (long)r * 1024 + t * 64, lds + d * 16384 + r * 64);
        }
    };
    auto stageB = [&](int t) {
        const int d = t & 1;
#pragma unroll
        for (int j = 0; j < 4; ++j) {
            const int r = wave * 8 + j * 64;
            gload16(bStageBase + (long)r * 1024 + t * 64,
                    lds + 32768 + d * 16384 + r * 64);
        }
    };

    // ---- hoisted DS read bases (element offsets into lds) ----
    const int laneR = lane & 15;
    const int sB0 = (((lane >> 4) ^ (lane & 7)) * 8);
    const int cA0 = wm * 8192 + laneR * 64 + sB0;              // kk=0
    const int cA1 = wm * 8192 + laneR * 64 + (sB0 ^ 32);       // kk=1
    const int cB0 = 32768 + (wn >> 1) * 8192 + (wn & 1) * 4096 +
                    laneR * 64 + sB0;
    const int cB1 = 32768 + (wn >> 1) * 8192 + (wn & 1) * 4096 +
                    laneR * 64 + (sB0 ^ 32);

    short8 alo[4][2], ahi[4][2], blo[2][2], bhi[2][2];
    auto rdAlo = [&](int pa0, int pa1) {
#pragma unroll
        for (int m = 0; m < 4; ++m) {
            alo[m][0] = *(const short8*)(lds + pa0 + m * 1024);
            alo[m][1] = *(const short8*)(lds + pa1 + m * 1024);
        }
    };
    auto rdAhi = [&](int pa0, int pa1) {
#pragma unroll
        for (int m = 0; m < 4; ++m) {
            ahi[m][0] = *(const short8*)(lds + pa0 + 4096 + m * 1024);
            ahi[m][1] = *(const short8*)(lds + pa1 + 4096 + m * 1024);
        }
    };
    auto rdBlo = [&](int pb0, int pb1) {
#pragma unroll
        for (int n = 0; n < 2; ++n) {
            blo[n][0] = *(const short8*)(lds + pb0 + n * 1024);
            blo[n][1] = *(const short8*)(lds + pb1 + n * 1024);
        }
    };
    auto rdBhi = [&](int pb0, int pb1) {
#pragma unroll
        for (int n = 0; n < 2; ++n) {
            bhi[n][0] = *(const short8*)(lds + pb0 + 2048 + n * 1024);
            bhi[n][1] = *(const short8*)(lds + pb1 + 2048 + n * 1024);
        }
    };
    // kk-OUTER: consecutive MFMAs touch different acc; same acc 8 apart.
    auto mm = [&](short8 (&a)[4][2], short8 (&b)[2][2], int mo, int no) {
        __builtin_amdgcn_s_setprio(1);
#pragma unroll
        for (int kk = 0; kk < 2; ++kk)
#pragma unroll
            for (int m = 0; m < 4; ++m)
#pragma unroll
                for (int n = 0; n < 2; ++n)
                    acc[mo + m][no + n] = __builtin_amdgcn_mfma_f32_16x16x32_bf16(
                        a[m][kk], b[n][kk], acc[mo + m][no + n], 0, 0, 0);
        __builtin_amdgcn_s_setprio(0);
    };

#define BAR()    __builtin_amdgcn_s_barrier()
#define LGKM0()  asm volatile("s_waitcnt lgkmcnt(0)" ::: "memory")
#define VMW0()   asm volatile("s_waitcnt vmcnt(0)" ::: "memory")
#define SCHED0() __builtin_amdgcn_sched_barrier(0)

    // -------- prologue: tile0 staged + visible --------
    stageA(0); stageB(0);
    VMW0();
    BAR();
    SCHED0();

#pragma unroll 2
    for (int t = 0; t < 16; ++t) {
        const int dofs = (t & 1) * 16384;
        const int pa0 = cA0 + dofs, pa1 = cA1 + dofs;
        const int pb0 = cB0 + dofs, pb1 = cB1 + dofs;
        // ---- P1: mm(alo,blo) ----  (no barrier: waves slip)
        if (t + 1 < 16) stageA(t + 1);
        rdAlo(pa0, pa1); rdBlo(pb0, pb1);   // 12 reads
        LGKM0(); SCHED0();
        mm(alo, blo, 0, 0);
        // ---- P2: mm(ahi,blo) ----
        if (t + 1 < 16) stageB(t + 1);
        rdAhi(pa0, pa1);                    // 8 reads
        LGKM0(); SCHED0();
        mm(ahi, blo, 4, 0);
        // ---- P3: mm(ahi,bhi) ----
        rdBhi(pb0, pb1);                    // 4 reads
        LGKM0(); SCHED0();
        mm(ahi, bhi, 4, 2);
        // ---- P4: mm(alo,bhi) + tile-end sync ----
        mm(alo, bhi, 0, 2);
        VMW0();                             // own stages landed
        BAR();                              // all waves' reads drained (their
        SCHED0();                           //  LGKM0s) + fresh tile visible
    }

    // ---------------- epilogue ----------------
    if (MODE == 0) {
        const int sec = (int)(n0 >> 10);        // 0=Q 1=K 2=V (uniform per block)
        short* outp = sec == 0 ? oQ : (sec == 1 ? oK : oV);
        const long cbase = n0 & 1023;
#pragma unroll
        for (int mi = 0; mi < 8; ++mi) {
#pragma unroll
            for (int r = 0; r < 4; ++r) {
                long gm = m0 + wm * 128 + mi * 16 + (lane >> 4) * 4 + r;
                int mz = (sec >= 1) ? mask[gm] : 0;
#pragma unroll
                for (int ni = 0; ni < 4; ++ni) {
                    long gn = cbase + wn * 64 + ni * 16 + (lane & 15);
                    float v = acc[mi][ni][r];
                    if (sec <= 1) v = (v > 0.f) ? v + 1.f : __expf(v);  // elu+1
                    if (mz) v = 0.f;
                    outp[gm * 1024 + gn] = f2b(v);
                }
            }
        }
    } else {
#pragma unroll
        for (int mi = 0; mi < 8; ++mi)
#pragma unroll
            for (int r = 0; r < 4; ++r) {
                long gm = m0 + wm * 128 + mi * 16 + (lane >> 4) * 4 + r;
#pragma unroll
                for (int ni = 0; ni < 4; ++ni) {
                    long gn = n0 + wn * 64 + ni * 16 + (lane & 15);
                    oF[gm * 1024 + gn] = acc[mi][ni][r];
                }
            }
    }
#undef BAR
#undef LGKM0
#undef VMW0
#undef SCHED0
}

// ------- kv via MFMA: kv[bh][dk][dv] = sum_t K[t][dk]*V[t][dv] (per chunk) ----
__global__ __launch_bounds__(256) void kv_mfma(
    const short* __restrict__ Kb, const short* __restrict__ Vb,
    float* __restrict__ kvp, float* __restrict__ ksp) {
    __shared__ __align__(16) short Kt[64 * 256];
    __shared__ __align__(16) short Vt[64 * 256];
    __shared__ float ksred[256];
    const int c = blockIdx.x, bh = blockIdx.y;
    const int b = bh >> 4, h = bh & 15;
    const int tid = threadIdx.x, wave = tid >> 6, lane = tid & 63;
    const long rowbase = (long)b * T_ + (long)c * 256;
    const int col0 = h * 64;

    for (int e = 0; e < 8; ++e) {
        int chunk = tid + e * 256;
        int trow = chunk >> 3;
        int c8 = (chunk & 7) * 8;
        short8 kv8 = *(const short8*)(Kb + (rowbase + trow) * 1024 + col0 + c8);
        short8 vv8 = *(const short8*)(Vb + (rowbase + trow) * 1024 + col0 + c8);
#pragma unroll
        for (int j = 0; j < 8; ++j) {
            int col = c8 + j;
            int tp = (trow & 7) | ((((trow >> 3) ^ (col & 7)) & 31) << 3);
            Kt[col * 256 + tp] = kv8[j];
            Vt[col * 256 + tp] = vv8[j];
        }
    }
    __syncthreads();

    const int lr = lane & 15, lk = lane >> 4;
    f32x4 acc[4];
#pragma unroll
    for (int m = 0; m < 4; ++m) acc[m] = (f32x4)(0.0f);
    for (int ts = 0; ts < 8; ++ts) {
        short8 bf;
        {
            int row = wave * 16 + lr;
            int slot = ((ts * 4 + lk) ^ (row & 7)) & 31;
            bf = *(const short8*)(Vt + row * 256 + slot * 8);
        }
#pragma unroll
        for (int m = 0; m < 4; ++m) {
            int row = m * 16 + lr;
            int slot = ((ts * 4 + lk) ^ (row & 7)) & 31;
            short8 af = *(const short8*)(Kt + row * 256 + slot * 8);
            acc[m] = __builtin_amdgcn_mfma_f32_16x16x32_bf16(af, bf, acc[m], 0, 0, 0);
        }
    }

    {
        int dk = tid & 63, q = tid >> 6;
        float s = 0.f;
#pragma unroll
        for (int j = 0; j < 8; ++j) {
            short8 v = *(const short8*)(Kt + dk * 256 + q * 64 + j * 8);
#pragma unroll
            for (int e2 = 0; e2 < 8; ++e2) s += b2f(v[e2]);
        }
        ksred[tid] = s;
    }
    __syncthreads();

    float* dst = kvp + ((long)bh * 16 + c) * 4096;
#pragma unroll
    for (int m = 0; m < 4; ++m)
#pragma unroll
        for (int r = 0; r < 4; ++r) {
            int dk = m * 16 + lk * 4 + r;
            dst[dk * 64 + wave * 16 + lr] = acc[m][r];
        }
    if (tid < 64) {
        float s = ksred[tid] + ksred[tid + 64] + ksred[tid + 128] + ksred[tid + 192];
        ksp[((long)bh * 16 + c) * 64 + tid] = s;
    }
}

// ---------------- reduce partials -> kvT_ext bf16 [bh][80][64] ----------------
__global__ __launch_bounds__(256) void kv_reduce(
    const float* __restrict__ kvp, const float* __restrict__ ksp,
    short* __restrict__ kvT) {
    const int bh = blockIdx.x;
    const int tid = threadIdx.x;
    for (int e = tid; e < 4096; e += 256) {
        int dk = e >> 6, dv = e & 63;
        float s = 0.f;
#pragma unroll
        for (int c = 0; c < 16; ++c) s += kvp[((long)bh * 16 + c) * 4096 + e];
        kvT[(long)bh * 5120 + dv * 64 + dk] = f2b(s);
    }
    if (tid < 64) {
        float s = 0.f;
#pragma unroll
        for (int c = 0; c < 16; ++c) s += ksp[((long)bh * 16 + c) * 64 + tid];
        kvT[(long)bh * 5120 + 64 * 64 + tid] = f2b(s);
    }
    for (int e = tid; e < 15 * 64; e += 256)
        kvT[(long)bh * 5120 + 65 * 64 + e] = 0;
}

// ---------------- attn out: out = (Q . kv) / max(Q.k_sum,1e-6) ----------------
__global__ __launch_bounds__(256) void attn_out(
    const short* __restrict__ Qb, const short* __restrict__ kvT,
    short* __restrict__ attn) {
    __shared__ __align__(16) short Qs[128 * 64];
    const int tb = blockIdx.x, bh = blockIdx.y;
    const int b = bh >> 4, h = bh & 15;
    const int tid = threadIdx.x, wave = tid >> 6, lane = tid & 63;
    const long trow0 = (long)b * T_ + (long)tb * 128;
    const int col0 = h * 64;

    const int lr = lane >> 3, lc = (lane & 7) * 8;
    const short* qsrc = Qb + (trow0 + wave * 8 + lr) * 1024 + col0 + lc;
#pragma unroll
    for (int is = 0; is < 4; ++is)
        gload16(qsrc + (long)is * 32 * 1024, Qs + is * 2048 + wave * 512);

    short8 bfr[5][2];
    const short* kvb = kvT + (long)bh * 5120;
#pragma unroll
    for (int nf = 0; nf < 5; ++nf)
#pragma unroll
        for (int kk = 0; kk < 2; ++kk)
            bfr[nf][kk] = *(const short8*)(kvb + (nf * 16 + (lane & 15)) * 64 +
                                           kk * 32 + (lane >> 4) * 8);
    __syncthreads();

#pragma unroll
    for (int tf = 0; tf < 2; ++tf) {
        short8 af[2];
        int ar = wave * 32 + tf * 16 + (lane & 15);
#pragma unroll
        for (int kk = 0; kk < 2; ++kk)
            af[kk] = *(const short8*)(Qs + ar * 64 + kk * 32 + (lane >> 4) * 8);
        f32x4 oacc[5];
#pragma unroll
        for (int nf = 0; nf < 5; ++nf) {
            oacc[nf] = (f32x4)(0.0f);
#pragma unroll
            for (int kk = 0; kk < 2; ++kk)
                oacc[nf] = __builtin_amdgcn_mfma_f32_16x16x32_bf16(
                    af[kk], bfr[nf][kk], oacc[nf], 0, 0, 0);
        }
#pragma unroll
        for (int r = 0; r < 4; ++r) {
            float nv = __shfl(oacc[4][r], lane & 48, 64);  // norm col of frag 4
            nv = fmaxf(nv, 1e-6f);
            long gm = trow0 + wave * 32 + tf * 16 + (lane >> 4) * 4 + r;
#pragma unroll
            for (int nf = 0; nf < 4; ++nf) {
                float v = oacc[nf][r] / nv;
                attn[gm * 1024 + col0 + nf * 16 + (lane & 15)] = f2b(v);
            }
        }
    }
}

// ---------------- launch ----------------
extern "C" void kernel_launch(void* const* d_in, const int* in_sizes, int n_in,
                              void* d_out, int out_size, void* d_ws, size_t ws_size,
                              hipStream_t stream) {
    const float* x = (const float*)d_in[0];
    const int* mask = (const int*)d_in[1];
    const float* Wq = (const float*)d_in[2];
    const float* Wk = (const float*)d_in[3];
    const float* Wv = (const float*)d_in[4];
    const float* Wo = (const float*)d_in[5];
    float* out = (float*)d_out;
    char* ws = (char*)d_ws;

    short* xb    = (short*)(ws);                 // 33554432 B
    short* wqkvb = (short*)(ws + 33554432);      //  6291456 B
    short* wob   = (short*)(ws + 39845888);      //  2097152 B
    short* Qb    = (short*)(ws + 41943040);      // 33554432 B
    short* Kb    = (short*)(ws + 75497472);      // 33554432 B
    short* Vb    = (short*)(ws + 109051904);     // 33554432 B
    float* kvp   = (float*)(ws + 142606336);     // 16777216 B
    float* ksp   = (float*)(ws + 159383552);     //   262144 B
    short* kvT   = (short*)(ws + 159645696);     //   655360 B
    short* attnb = xb;  // x dead after projection GEMM; reuse

    hipFuncSetAttribute((const void*)gemm4s<0>,
                        hipFuncAttributeMaxDynamicSharedMemorySize, 131072);
    hipFuncSetAttribute((const void*)gemm4s<1>,
                        hipFuncAttributeMaxDynamicSharedMemorySize, 131072);

    cvt_all<<<20480, 256, 0, stream>>>(x, Wq, Wk, Wv, Wo, xb, wqkvb, wob);
    gemm4s<0><<<768, 512, 131072, stream>>>(xb, wqkvb, mask, Qb, Kb, Vb, nullptr);
    kv_mfma<<<dim3(16, 64), 256, 0, stream>>>(Kb, Vb, kvp, ksp);
    kv_reduce<<<64, 256, 0, stream>>>(kvp, ksp, kvT);
    attn_out<<<dim3(32, 64), 256, 0, stream>>>(Qb, kvT, attnb);
    gemm4s<1><<<256, 512, 131072, stream>>>(attnb, wob, nullptr, nullptr, nullptr,
                                            nullptr, out);
}